// Round 1
// baseline (4149.130 us; speedup 1.0000x reference)
//
#include <hip/hip_runtime.h>

typedef unsigned short ushort;
typedef unsigned int uint;

#define DEV __device__ __forceinline__

typedef __attribute__((ext_vector_type(4))) float f32x4;
typedef __bf16 bf16x8 __attribute__((ext_vector_type(8)));

static constexpr int B_ = 4, L_ = 4096, D_ = 512;
static constexpr long NE = (long)B_ * L_ * D_;      // 8388608
static constexpr int ROWS = B_ * L_;                // 16384

// ---------------- small helpers ----------------
DEV float b2f(ushort u) { return __uint_as_float(((uint)u) << 16); }
DEV ushort f2b(float f) {
    uint u = __float_as_uint(f);
    uint r = u + 0x7FFFu + ((u >> 16) & 1u);
    return (ushort)(r >> 16);
}
DEV uint mapF(float f) {
    uint b = __float_as_uint(f);
    return (b & 0x80000000u) ? ~b : (b | 0x80000000u);
}
DEV float unmapF(uint u) {
    uint b = (u & 0x80000000u) ? (u & 0x7FFFFFFFu) : ~u;
    return __uint_as_float(b);
}
DEV float sigm(float x) { return 1.f / (1.f + expf(-x)); }

// trigamma(t+1), t in (-1,1): psi1(x) = sum_{k=0..5} 1/(x+k)^2 + asym(x+6)
DEV float trigamma1p(float t) {
    float x = t + 1.f;
    float acc = 0.f;
#pragma unroll
    for (int k = 0; k < 6; k++) { float xx = x + (float)k; acc += 1.f / (xx * xx); }
    float y = x + 6.f;
    float iy = 1.f / y, iy2 = iy * iy;
    return acc + iy * (1.f + iy * (0.5f + iy * (0.166666667f + iy2 * (-0.0333333333f + iy2 * 0.0238095238f))));
}
// I1(t), |t|<~1.2: power series
DEV float besselI1(float t) {
    float q = 0.25f * t * t;
    return 0.5f * t * (1.f + q * (0.5f + q * (0.0833333333f + q * (0.00694444444f + q * (3.47222222e-4f + q * 1.15740741e-5f)))));
}
// Tprime = mix0*trigamma(t+1) + mix1*I1(t);  H = beta * Tprime * erf'(u)
DEV float rippleH(float u, float beta, float mix0, float mix1) {
    float t = beta * erff(u);
    float Tp = mix0 * trigamma1p(t) + mix1 * besselI1(t);
    float ep = 1.12837917f * expf(-u * u);
    return beta * Tp * ep;
}

// ---------------- GEMM: C[M,N] = A[M,K] * Bt[N,K]^T  (bf16 in, f32 accum) ----------------
// MODE 0: f32 out; 1: bf16 out; 2: atomic row-max into poolU (mapped uint); 3: f32 out scaled by rowScale[row]
template <int MODE>
__global__ __launch_bounds__(256, 2) void gemm_bt(
    const ushort* __restrict__ A, int lda,
    const ushort* __restrict__ Bt, int ldb,
    void* __restrict__ Cv, int ldc, int K,
    uint* __restrict__ poolU, const float* __restrict__ rowScale)
{
    __shared__ ushort Alds[128 * 32];
    __shared__ ushort Blds[128 * 32];
    const int tid = threadIdx.x;
    const int lane = tid & 63;
    const int wave = tid >> 6;
    const int wr = wave >> 1, wc = wave & 1;
    const int row0 = blockIdx.y * 128, col0 = blockIdx.x * 128;

    f32x4 acc[4][4] = {};

    const int r0c = tid >> 2;             // 0..63
    const int kc0 = (tid & 3) * 8;        // 0,8,16,24
    const ushort* Arow0 = A + (size_t)(row0 + r0c) * lda + kc0;
    const ushort* Arow1 = A + (size_t)(row0 + r0c + 64) * lda + kc0;
    const ushort* Brow0 = Bt + (size_t)(col0 + r0c) * ldb + kc0;
    const ushort* Brow1 = Bt + (size_t)(col0 + r0c + 64) * ldb + kc0;
    ushort* Asl0 = &Alds[r0c * 32 + kc0];
    ushort* Asl1 = &Alds[(r0c + 64) * 32 + kc0];
    ushort* Bsl0 = &Blds[r0c * 32 + kc0];
    ushort* Bsl1 = &Blds[(r0c + 64) * 32 + kc0];

    const int ar = wr * 64 + (lane & 15);
    const int br = wc * 64 + (lane & 15);
    const int kk = (lane >> 4) * 8;

    for (int k0 = 0; k0 < K; k0 += 32) {
        __syncthreads();
        *(bf16x8*)Asl0 = *(const bf16x8*)(Arow0 + k0);
        *(bf16x8*)Asl1 = *(const bf16x8*)(Arow1 + k0);
        *(bf16x8*)Bsl0 = *(const bf16x8*)(Brow0 + k0);
        *(bf16x8*)Bsl1 = *(const bf16x8*)(Brow1 + k0);
        __syncthreads();
        bf16x8 af[4], bfr[4];
#pragma unroll
        for (int mi = 0; mi < 4; mi++) af[mi] = *(const bf16x8*)&Alds[(ar + mi * 16) * 32 + kk];
#pragma unroll
        for (int ni = 0; ni < 4; ni++) bfr[ni] = *(const bf16x8*)&Blds[(br + ni * 16) * 32 + kk];
#pragma unroll
        for (int mi = 0; mi < 4; mi++)
#pragma unroll
            for (int ni = 0; ni < 4; ni++)
                acc[mi][ni] = __builtin_amdgcn_mfma_f32_16x16x32_bf16(af[mi], bfr[ni], acc[mi][ni], 0, 0, 0);
    }

    const int orow = row0 + wr * 64;
    const int ocol = col0 + wc * 64 + (lane & 15);
    if (MODE == 2) {
#pragma unroll
        for (int mi = 0; mi < 4; mi++) {
#pragma unroll
            for (int j = 0; j < 4; j++) {
                float v = acc[mi][0][j];
                v = fmaxf(v, acc[mi][1][j]); v = fmaxf(v, acc[mi][2][j]); v = fmaxf(v, acc[mi][3][j]);
#pragma unroll
                for (int off = 1; off < 16; off <<= 1) v = fmaxf(v, __shfl_xor(v, off));
                if ((lane & 15) == 0) {
                    int r = orow + mi * 16 + (lane >> 4) * 4 + j;
                    atomicMax(&poolU[r], mapF(v));
                }
            }
        }
    } else {
#pragma unroll
        for (int mi = 0; mi < 4; mi++) {
            const int rbase = orow + mi * 16 + (lane >> 4) * 4;
#pragma unroll
            for (int j = 0; j < 4; j++) {
                float sc = (MODE == 3) ? rowScale[rbase + j] : 1.f;
#pragma unroll
                for (int ni = 0; ni < 4; ni++) {
                    float v = acc[mi][ni][j] * sc;
                    int cc = ocol + ni * 16;
                    if (MODE == 1) ((ushort*)Cv)[(size_t)(rbase + j) * ldc + cc] = f2b(v);
                    else ((float*)Cv)[(size_t)(rbase + j) * ldc + cc] = v;
                }
            }
        }
    }
}

// ---------------- misc kernels ----------------
__global__ void convert_f2b_k(const float* __restrict__ s, ushort* __restrict__ d, long n) {
    long i = (long)blockIdx.x * blockDim.x + threadIdx.x;
    long st = (long)gridDim.x * blockDim.x;
    for (; i < n; i += st) d[i] = f2b(s[i]);
}

template <bool SRCF32>
__global__ __launch_bounds__(256) void transpose_to_bf16(const void* __restrict__ srcv, ushort* __restrict__ dst, int R, int C) {
    __shared__ float tile[32][33];
    const int z = blockIdx.z;
    const float* sf = (const float*)srcv + (size_t)z * R * C;
    const ushort* sb = (const ushort*)srcv + (size_t)z * R * C;
    ushort* dz = dst + (size_t)z * R * C;
    const int tx = threadIdx.x & 31, ty = threadIdx.x >> 5;
    const int c = blockIdx.x * 32 + tx;
#pragma unroll
    for (int k = 0; k < 4; k++) {
        const int r = blockIdx.y * 32 + ty + k * 8;
        tile[ty + k * 8][tx] = SRCF32 ? sf[(size_t)r * C + c] : b2f(sb[(size_t)r * C + c]);
    }
    __syncthreads();
#pragma unroll
    for (int k = 0; k < 4; k++) {
        const int dr = blockIdx.x * 32 + ty + k * 8;
        const int dc = blockIdx.y * 32 + tx;
        dz[(size_t)dr * R + dc] = f2b(tile[tx][ty + k * 8]);
    }
}

__global__ void init_pool_k(uint* poolU) {
    int i = blockIdx.x * 256 + threadIdx.x;
    if (i < 2048) poolU[i] = 0u;
}
__global__ void sentinel_k(float* o) { o[threadIdx.x] = 1.0e6f; }

// gates elementwise: nx = x*sigmoid(gxa)*sqrt(1-exp(2*la)); ea = exp(la); la = -8*softplus(a)*sigmoid(gaa)
__global__ void gates_elem_k(const float* __restrict__ x, const float* __restrict__ gxa, const float* __restrict__ gaa,
                             const float* __restrict__ a_param, ushort* __restrict__ nxb, ushort* __restrict__ eab) {
    long i = (long)blockIdx.x * blockDim.x + threadIdx.x;
    long st = (long)gridDim.x * blockDim.x;
    for (; i < NE; i += st) {
        int d = (int)(i & 511);
        float gx = sigm(gxa[i]);
        float ga = sigm(gaa[i]);
        float a = a_param[d];
        float sp = fmaxf(a, 0.f) + log1pf(expf(-fabsf(a)));
        float la = -8.f * sp * ga;
        float ea = expf(la);
        float nx = x[i] * gx * sqrtf(fmaxf(1.f - expf(2.f * la), 0.f));
        nxb[i] = f2b(nx);
        eab[i] = f2b(ea);
    }
}

// row softmax over N=4096 bf16 -> bf16 (for attention P)
__global__ __launch_bounds__(256) void softmax_rows_k(const ushort* __restrict__ S, ushort* __restrict__ P, float scale) {
    __shared__ float red[256];
    const int tid = threadIdx.x;
    const ushort* row = S + (size_t)blockIdx.x * 4096;
    float vals[16];
    bf16x8 v0 = *(const bf16x8*)&row[tid * 16];
    bf16x8 v1 = *(const bf16x8*)&row[tid * 16 + 8];
    float mx = -3.4e38f;
#pragma unroll
    for (int k = 0; k < 8; k++) { vals[k] = (float)v0[k] * scale; mx = fmaxf(mx, vals[k]); }
#pragma unroll
    for (int k = 0; k < 8; k++) { vals[8 + k] = (float)v1[k] * scale; mx = fmaxf(mx, vals[8 + k]); }
    red[tid] = mx; __syncthreads();
    for (int s = 128; s > 0; s >>= 1) { if (tid < s) red[tid] = fmaxf(red[tid], red[tid + s]); __syncthreads(); }
    mx = red[0]; __syncthreads();
    float sum = 0.f;
#pragma unroll
    for (int k = 0; k < 16; k++) { vals[k] = expf(vals[k] - mx); sum += vals[k]; }
    red[tid] = sum; __syncthreads();
    for (int s = 128; s > 0; s >>= 1) { if (tid < s) red[tid] += red[tid + s]; __syncthreads(); }
    float inv = 1.f / red[0];
    ushort* prow = P + (size_t)blockIdx.x * 4096;
#pragma unroll
    for (int k = 0; k < 16; k++) prow[tid * 16 + k] = f2b(vals[k] * inv);
}

// gated = ea*pool[b,d] + nx  (bf16 out)
__global__ void gated_k(const ushort* __restrict__ eab, const ushort* __restrict__ nxb,
                        const uint* __restrict__ poolU, ushort* __restrict__ gatedb) {
    long i = (long)blockIdx.x * blockDim.x + threadIdx.x;
    long st = (long)gridDim.x * blockDim.x;
    for (; i < NE; i += st) {
        int d = (int)(i & 511);
        int b = (int)(i >> 21);
        float pl = unmapF(poolU[b * 512 + d]);
        gatedb[i] = f2b(b2f(eab[i]) * pl + b2f(nxb[i]));
    }
}

// global max + argmax (stage1)
__global__ __launch_bounds__(256) void redmax1_k(const float* __restrict__ d, float* __restrict__ bmax, int* __restrict__ bidx) {
    __shared__ float rv[256];
    __shared__ int ri[256];
    const int tid = threadIdx.x;
    long g = (long)blockIdx.x * 256 + tid;
    const long stride = (long)gridDim.x * 256;
    float bv = -3.4e38f; int bi = -1;
    for (long i = g; i < NE; i += stride) {
        float v = d[i];
        if (v > bv) { bv = v; bi = (int)i; }
    }
    rv[tid] = bv; ri[tid] = bi; __syncthreads();
    for (int s = 128; s > 0; s >>= 1) {
        if (tid < s) {
            float ov = rv[tid + s]; int oi = ri[tid + s];
            if (oi >= 0 && (ri[tid] < 0 || ov > rv[tid] || (ov == rv[tid] && oi < ri[tid]))) { rv[tid] = ov; ri[tid] = oi; }
        }
        __syncthreads();
    }
    if (tid == 0) { bmax[blockIdx.x] = rv[0]; bidx[blockIdx.x] = ri[0]; }
}
__global__ __launch_bounds__(256) void redmax2_k(const float* __restrict__ bmax, const int* __restrict__ bidx, int n,
                                                 float* __restrict__ outM, int* __restrict__ outI) {
    __shared__ float rv[256];
    __shared__ int ri[256];
    const int tid = threadIdx.x;
    float bv = -3.4e38f; int bi = -1;
    for (int i = tid; i < n; i += 256) {
        float v = bmax[i]; int ix = bidx[i];
        if (ix >= 0 && (bi < 0 || v > bv || (v == bv && ix < bi))) { bv = v; bi = ix; }
    }
    rv[tid] = bv; ri[tid] = bi; __syncthreads();
    for (int s = 128; s > 0; s >>= 1) {
        if (tid < s) {
            float ov = rv[tid + s]; int oi = ri[tid + s];
            if (oi >= 0 && (ri[tid] < 0 || ov > rv[tid] || (ov == rv[tid] && oi < ri[tid]))) { rv[tid] = ov; ri[tid] = oi; }
        }
        __syncthreads();
    }
    if (tid == 0) { outM[0] = rv[0]; outI[0] = ri[0]; }
}

// ripple gradient base: gb = beta*T'(t)*erf'(u)/(M*alpha); partial SS = sum beta*T'*erf'*d
__global__ __launch_bounds__(256) void ripple_g_k(const float* __restrict__ d, float* __restrict__ gb, float* __restrict__ sspart,
                                                  const float* __restrict__ scalM, const float* __restrict__ alpha_p,
                                                  const float* __restrict__ beta_p, const float* __restrict__ mix_p) {
    __shared__ float red[256];
    const int tid = threadIdx.x;
    const float M = scalM[0];
    const float alpha = alpha_p[0], beta = beta_p[0];
    float m0 = mix_p[0], m1 = mix_p[1];
    float mm = fmaxf(m0, m1);
    float e0 = expf(m0 - mm), e1 = expf(m1 - mm);
    float inv = 1.f / (e0 + e1);
    float mix0 = e0 * inv, mix1 = e1 * inv;
    const float invMA = 1.f / (M * alpha);
    float ss = 0.f;
    long g = (long)blockIdx.x * 256 + tid;
    const long stride = (long)gridDim.x * 256;
    for (long i = g; i < NE; i += stride) {
        float dv = d[i];
        float H = rippleH(dv * invMA, beta, mix0, mix1);
        gb[i] = H * invMA;
        ss += H * dv;
    }
    red[tid] = ss; __syncthreads();
    for (int s = 128; s > 0; s >>= 1) { if (tid < s) red[tid] += red[tid + s]; __syncthreads(); }
    if (tid == 0) sspart[blockIdx.x] = red[0];
}
__global__ __launch_bounds__(256) void redsum2_k(const float* __restrict__ part, int n, float* __restrict__ out) {
    __shared__ float red[256];
    const int tid = threadIdx.x;
    float s = 0.f;
    for (int i = tid; i < n; i += 256) s += part[i];
    red[tid] = s; __syncthreads();
    for (int q = 128; q > 0; q >>= 1) { if (tid < q) red[tid] += red[tid + q]; __syncthreads(); }
    if (tid == 0) out[0] = red[0];
}

// per-row (512) softmin: g = clip(gb - (i==amax)*SS/(M^2*alpha)); p = softmax(-g); out = bf16(p [* gated])
template <int GS>
__global__ __launch_bounds__(256) void ripple_softmax_k(const float* __restrict__ gb,
                                                        const float* __restrict__ scalM, const int* __restrict__ scalI,
                                                        const float* __restrict__ ssTot, const float* __restrict__ alpha_p,
                                                        const ushort* __restrict__ gatedb, ushort* __restrict__ outb) {
    __shared__ float red[256];
    const int tid = threadIdx.x;
    const float M = scalM[0];
    const int amax = scalI[0];
    const float corr = ssTot[0] / (M * M * alpha_p[0]);
    long base = (long)blockIdx.x * 512;
    float g0 = gb[base + tid];
    float g1 = gb[base + tid + 256];
    if ((int)(base + tid) == amax) g0 -= corr;
    if ((int)(base + tid + 256) == amax) g1 -= corr;
    g0 = fminf(fmaxf(g0, -1.f), 1.f);
    g1 = fminf(fmaxf(g1, -1.f), 1.f);
    float mn = fminf(g0, g1);
    red[tid] = mn; __syncthreads();
    for (int s = 128; s > 0; s >>= 1) { if (tid < s) red[tid] = fminf(red[tid], red[tid + s]); __syncthreads(); }
    mn = red[0]; __syncthreads();
    float e0 = expf(mn - g0), e1 = expf(mn - g1);
    red[tid] = e0 + e1; __syncthreads();
    for (int s = 128; s > 0; s >>= 1) { if (tid < s) red[tid] += red[tid + s]; __syncthreads(); }
    float inv = 1.f / red[0];
    if (GS) {
        outb[base + tid] = f2b(b2f(gatedb[base + tid]) * (e0 * inv));
        outb[base + tid + 256] = f2b(b2f(gatedb[base + tid + 256]) * (e1 * inv));
    } else {
        outb[base + tid] = f2b(e0 * inv);
        outb[base + tid + 256] = f2b(e1 * inv);
    }
}

// token selection stage 1: per row, scores for 4 heads -> combined, vals
__global__ __launch_bounds__(256) void ts1_k(const float* __restrict__ x, const float* __restrict__ cls_w,
                                             const float* __restrict__ cls_b, const float* __restrict__ tw,
                                             const float* __restrict__ prelu_a,
                                             float* __restrict__ combined, float* __restrict__ vals) {
    __shared__ float cw[2048];
    const int tid = threadIdx.x;
    for (int i = tid; i < 2048; i += 256) cw[i] = cls_w[i];
    __syncthreads();
    const int lane = tid & 63, wid = tid >> 6;
    const int row = blockIdx.x * 4 + wid;
    const float* xr = x + (size_t)row * 512 + lane * 8;
    float pa0 = 0, pa1 = 0, pa2 = 0, pa3 = 0;
#pragma unroll
    for (int j = 0; j < 8; j++) {
        float v = xr[j];
        int c = lane * 8 + j;
        pa0 += v * cw[c]; pa1 += v * cw[512 + c]; pa2 += v * cw[1024 + c]; pa3 += v * cw[1536 + c];
    }
#pragma unroll
    for (int o = 32; o > 0; o >>= 1) {
        pa0 += __shfl_down(pa0, o); pa1 += __shfl_down(pa1, o);
        pa2 += __shfl_down(pa2, o); pa3 += __shfl_down(pa3, o);
    }
    if (lane == 0) {
        float a = prelu_a[0];
        float sc[4] = {pa0, pa1, pa2, pa3};
        float comb = 0.f, vsum = 0.f;
#pragma unroll
        for (int s = 0; s < 4; s++) {
            float p = sc[s] + cls_b[s];
            p = (p >= 0.f) ? p : a * p;
            float cel = (p > 0.f) ? p : expm1f(p);
            float sil = p * sigm(p);
            float gel = 0.5f * p * (1.f + erff(p * 0.70710678f));
            float ts = cel * sil + gel;
            float ww = tw[s];
            float se = 1.05070099f * ((ww > 0.f) ? ww : 1.67326324f * expm1f(ww));
            comb += se * ts;
            vsum += ts;
        }
        combined[row] = comb;
        vals[row] = vsum;
    }
}

// token selection stage 2: rank (stable descending) -> importance[p] = 1 + vals[rank(p)]
__global__ __launch_bounds__(256) void ts2_k(const float* __restrict__ combined, const float* __restrict__ vals,
                                             float* __restrict__ imp) {
    __shared__ float c[4096];
    const int b = blockIdx.x;
    const int tid = threadIdx.x;
    const float* cr = combined + b * 4096;
    for (int i = tid; i < 4096; i += 256) c[i] = cr[i];
    __syncthreads();
    float cp[16]; int rank[16];
#pragma unroll
    for (int k = 0; k < 16; k++) { cp[k] = c[tid + k * 256]; rank[k] = 0; }
    for (int q = 0; q < 4096; q++) {
        float cq = c[q];
#pragma unroll
        for (int k = 0; k < 16; k++)
            rank[k] += (cq > cp[k]) || (cq == cp[k] && q < (tid + k * 256));
    }
#pragma unroll
    for (int k = 0; k < 16; k++)
        imp[b * 4096 + tid + k * 256] = 1.f + vals[b * 4096 + rank[k]];
}

// token selection stage 3: ripplemoe over [B,L] -> sel = 1 + softmax(-g, axis=L)
__global__ __launch_bounds__(256) void ts3_k(const float* __restrict__ imp, float* __restrict__ gmoe, float* __restrict__ sel,
                                             const float* __restrict__ tsw, const float* __restrict__ tsa,
                                             const float* __restrict__ tsb, const float* __restrict__ tsmix) {
    __shared__ float red[256];
    __shared__ int ri[256];
    __shared__ float sM, sSS;
    __shared__ int sAmax;
    const int tid = threadIdx.x;
    // head weights softmax
    float w[4];
    {
        float wm = fmaxf(fmaxf(tsw[0], tsw[1]), fmaxf(tsw[2], tsw[3]));
        float s = 0.f;
#pragma unroll
        for (int k = 0; k < 4; k++) { w[k] = expf(tsw[k] - wm); s += w[k]; }
#pragma unroll
        for (int k = 0; k < 4; k++) w[k] /= s;
    }
    const float beta = tsb[0];
    float m0 = tsmix[0], m1 = tsmix[1];
    float mm = fmaxf(m0, m1);
    float e0 = expf(m0 - mm), e1 = expf(m1 - mm);
    float minv = 1.f / (e0 + e1);
    const float mix0 = e0 * minv, mix1 = e1 * minv;

    // phase 1: global max/argmax over 65536
    float bv = -3.4e38f; int bi = -1;
    for (int i = tid; i < 65536; i += 256) {
        float v = imp[i];
        if (v > bv) { bv = v; bi = i; }
    }
    red[tid] = bv; ri[tid] = bi; __syncthreads();
    for (int s = 128; s > 0; s >>= 1) {
        if (tid < s) {
            float ov = red[tid + s]; int oi = ri[tid + s];
            if (oi >= 0 && (ri[tid] < 0 || ov > red[tid] || (ov == red[tid] && oi < ri[tid]))) { red[tid] = ov; ri[tid] = oi; }
        }
        __syncthreads();
    }
    if (tid == 0) { sM = red[0]; sAmax = ri[0]; }
    __syncthreads();
    const float M = sM;

    // phase 2: gbase + SS
    float ss = 0.f;
    for (int i = tid; i < 65536; i += 256) {
        float dv = imp[i];
        float gbv = 0.f;
#pragma unroll
        for (int s = 0; s < 4; s++) {
            float al = tsa[s];
            float H = rippleH(dv / (M * al), beta, mix0, mix1);
            gbv += w[s] * H / (M * al);
            ss += w[s] * H * dv / al;
        }
        gmoe[i] = gbv;
    }
    __syncthreads();
    red[tid] = ss; __syncthreads();
    for (int s = 128; s > 0; s >>= 1) { if (tid < s) red[tid] += red[tid + s]; __syncthreads(); }
    if (tid == 0) sSS = red[0];
    __syncthreads();

    // phase 3: argmax correction + clip
    for (int i = tid; i < 65536; i += 256) {
        float g = gmoe[i];
        if (i == sAmax) g -= sSS / (M * M);
        gmoe[i] = fminf(fmaxf(g, -1.f), 1.f);
    }
    __syncthreads();

    // phase 4: per-batch-row softmax over L -> sel = 1 + p
    for (int b = 0; b < 4; b++) {
        float mn = 3.4e38f;
        for (int j = tid; j < 4096; j += 256) mn = fminf(mn, gmoe[b * 4096 + j]);
        red[tid] = mn; __syncthreads();
        for (int s = 128; s > 0; s >>= 1) { if (tid < s) red[tid] = fminf(red[tid], red[tid + s]); __syncthreads(); }
        float rmn = red[0]; __syncthreads();
        float s2 = 0.f;
        for (int j = tid; j < 4096; j += 256) s2 += expf(rmn - gmoe[b * 4096 + j]);
        red[tid] = s2; __syncthreads();
        for (int s = 128; s > 0; s >>= 1) { if (tid < s) red[tid] += red[tid + s]; __syncthreads(); }
        float inv = 1.f / red[0]; __syncthreads();
        for (int j = tid; j < 4096; j += 256)
            sel[b * 4096 + j] = 1.f + expf(rmn - gmoe[b * 4096 + j]) * inv;
        __syncthreads();
    }
}

// ---------------- workspace layout (bytes) ----------------
static constexpr size_t OFF_XB    = 0;                       // ushort NE   (later: probs2b)
static constexpr size_t OFF_TMPB  = 16777216;                // ushort NE   (later: gsb)
static constexpr size_t OFF_SPB   = 33554432;                // ushort NE
static constexpr size_t OFF_SPT   = 50331648;                // ushort NE   ([4][512][4096])
static constexpr size_t OFF_DBUF  = 67108864;                // float NE    (gxa / Sb / d1 / attn)
static constexpr size_t OFF_HBUF  = 100663296;               // float NE    (gaa / P / H)
static constexpr size_t OFF_GATB  = 134217728;               // ushort NE
static constexpr size_t OFF_NXB   = 150994944;               // ushort NE
static constexpr size_t OFF_EAB   = 167772160;               // ushort NE
static constexpr size_t OFF_AST   = 184549376;               // 512*512 ushort
static constexpr size_t OFF_WSP   = 185073664;
static constexpr size_t OFF_WSIL  = 185597952;
static constexpr size_t OFF_WOH   = 186122240;
static constexpr size_t OFF_WOUT  = 186646528;
static constexpr size_t OFF_WIGT  = 187170816;               // 4*128*128 ushort
static constexpr size_t OFF_WAGT  = 187301888;
static constexpr size_t OFF_POOL  = 187432960;               // 2048 uint
static constexpr size_t OFF_SCAL  = 187441152;               // 64 float
static constexpr size_t OFF_SCALI = 187441408;               // 64 int
static constexpr size_t OFF_BMAX  = 187441664;               // 2048 float
static constexpr size_t OFF_BIDX  = 187449856;               // 2048 int
static constexpr size_t OFF_SSP   = 187458048;               // 2048 float
static constexpr size_t OFF_COMB  = 187466240;               // 65536 float
static constexpr size_t OFF_VALS  = 187728384;
static constexpr size_t OFF_IMP   = 187990528;
static constexpr size_t OFF_GMOE  = 188252672;
static constexpr size_t OFF_SEL   = 188514816;
static constexpr size_t WS_NEED   = 188776960;

extern "C" void kernel_launch(void* const* d_in, const int* in_sizes, int n_in,
                              void* d_out, int out_size, void* d_ws, size_t ws_size,
                              hipStream_t stream)
{
    (void)in_sizes; (void)n_in; (void)out_size;
    const float* x    = (const float*)d_in[0];
    const float* AS   = (const float*)d_in[1];
    const float* Wsp  = (const float*)d_in[2];
    const float* Wsil = (const float*)d_in[3];
    const float* Woh  = (const float*)d_in[4];
    const float* Wout = (const float*)d_in[5];
    const float* wig  = (const float*)d_in[6];
    const float* wag  = (const float*)d_in[7];
    const float* a_param = (const float*)d_in[8];
    const float* cls_w = (const float*)d_in[9];
    const float* cls_b = (const float*)d_in[10];
    const float* tokw  = (const float*)d_in[11];
    const float* prelu = (const float*)d_in[12];
    const float* tsw   = (const float*)d_in[13];
    const float* tsa   = (const float*)d_in[14];
    const float* tsb   = (const float*)d_in[15];
    const float* tsmix = (const float*)d_in[16];
    const float* p1a = (const float*)d_in[17];
    const float* p1b = (const float*)d_in[18];
    const float* p1m = (const float*)d_in[19];
    const float* p2a = (const float*)d_in[20];
    const float* p2b = (const float*)d_in[21];
    const float* p2m = (const float*)d_in[22];
    float* out = (float*)d_out;

    char* w = (char*)d_ws;
    if (ws_size < WS_NEED) { sentinel_k<<<1, 256, 0, stream>>>(out); return; }

    ushort* xb    = (ushort*)(w + OFF_XB);
    ushort* tmpb  = (ushort*)(w + OFF_TMPB);
    ushort* spb   = (ushort*)(w + OFF_SPB);
    ushort* spT   = (ushort*)(w + OFF_SPT);
    float*  dbuf  = (float*)(w + OFF_DBUF);
    float*  Hbuf  = (float*)(w + OFF_HBUF);
    ushort* Sb    = (ushort*)(w + OFF_DBUF);   // alias
    ushort* Pb    = (ushort*)(w + OFF_HBUF);   // alias
    float*  gxa   = (float*)(w + OFF_DBUF);    // alias
    float*  gaa   = (float*)(w + OFF_HBUF);    // alias
    ushort* gatedb= (ushort*)(w + OFF_GATB);
    ushort* nxb   = (ushort*)(w + OFF_NXB);
    ushort* eab   = (ushort*)(w + OFF_EAB);
    ushort* ASt   = (ushort*)(w + OFF_AST);
    ushort* Wspb  = (ushort*)(w + OFF_WSP);
    ushort* Wsilb = (ushort*)(w + OFF_WSIL);
    ushort* Wohb  = (ushort*)(w + OFF_WOH);
    ushort* Woutb = (ushort*)(w + OFF_WOUT);
    ushort* wigT  = (ushort*)(w + OFF_WIGT);
    ushort* wagT  = (ushort*)(w + OFF_WAGT);
    uint*   poolU = (uint*)(w + OFF_POOL);
    float*  scal  = (float*)(w + OFF_SCAL);
    int*    scalI = (int*)(w + OFF_SCALI);
    float*  bmax  = (float*)(w + OFF_BMAX);
    int*    bidx  = (int*)(w + OFF_BIDX);
    float*  sspart= (float*)(w + OFF_SSP);
    float*  comb  = (float*)(w + OFF_COMB);
    float*  vals  = (float*)(w + OFF_VALS);
    float*  imp   = (float*)(w + OFF_IMP);
    float*  gmoe  = (float*)(w + OFF_GMOE);
    float*  sel   = (float*)(w + OFF_SEL);
    ushort* gsb     = tmpb;   // reuse
    ushort* probs2b = xb;     // reuse

    // ---- prep ----
    convert_f2b_k<<<4096, 256, 0, stream>>>(x, xb, NE);
    convert_f2b_k<<<256, 256, 0, stream>>>(Wsp, Wspb, 262144);
    convert_f2b_k<<<256, 256, 0, stream>>>(Wsil, Wsilb, 262144);
    convert_f2b_k<<<256, 256, 0, stream>>>(Woh, Wohb, 262144);
    convert_f2b_k<<<256, 256, 0, stream>>>(Wout, Woutb, 262144);
    transpose_to_bf16<true><<<dim3(16, 16, 1), 256, 0, stream>>>(AS, ASt, 512, 512);
    transpose_to_bf16<true><<<dim3(4, 4, 4), 256, 0, stream>>>(wig, wigT, 128, 128);
    transpose_to_bf16<true><<<dim3(4, 4, 4), 256, 0, stream>>>(wag, wagT, 128, 128);
    init_pool_k<<<8, 256, 0, stream>>>(poolU);

    // ---- G1: tmp = x @ AS ; G2: spatial = tmp @ Wsp^T ----
    gemm_bt<1><<<dim3(4, 128), 256, 0, stream>>>(xb, 512, ASt, 512, tmpb, 512, 512, nullptr, nullptr);
    gemm_bt<1><<<dim3(4, 128), 256, 0, stream>>>(tmpb, 512, Wspb, 512, spb, 512, 512, nullptr, nullptr);

    // ---- gates: block-diag GEMMs then elementwise ----
    for (int h = 0; h < 4; h++) {
        gemm_bt<0><<<dim3(1, 128), 256, 0, stream>>>(xb + h * 128, 512, wigT + h * 16384, 128, gxa + h * 128, 512, 128, nullptr, nullptr);
        gemm_bt<0><<<dim3(1, 128), 256, 0, stream>>>(xb + h * 128, 512, wagT + h * 16384, 128, gaa + h * 128, 512, 128, nullptr, nullptr);
    }
    gates_elem_k<<<4096, 256, 0, stream>>>(x, gxa, gaa, a_param, nxb, eab);

    // ---- attention pool (per batch): S = sp sp^T ; P = softmax(S/sqrt(128)) ; pool = rowmax(spT P^T) ----
    transpose_to_bf16<false><<<dim3(16, 128, 4), 256, 0, stream>>>(spb, spT, 4096, 512);
    const float sc128 = 0.0883883476f;
    for (int b = 0; b < 4; b++) {
        const ushort* spB = spb + (size_t)b * L_ * D_;
        gemm_bt<1><<<dim3(32, 32), 256, 0, stream>>>(spB, 512, spB, 512, Sb, 4096, 512, nullptr, nullptr);
        softmax_rows_k<<<4096, 256, 0, stream>>>(Sb, Pb, sc128);
        gemm_bt<2><<<dim3(32, 4), 256, 0, stream>>>(spT + (size_t)b * D_ * L_, 4096, Pb, 4096, nullptr, 0, 4096, poolU + b * 512, nullptr);
    }

    // ---- gated = exp(log_a)*pool + nx ----
    gated_k<<<4096, 256, 0, stream>>>(eab, nxb, poolU, gatedb);

    // ---- sparsity = ripple_act(gated @ Wsil^T) ; gs = gated * sparsity ----
    gemm_bt<0><<<dim3(4, 128), 256, 0, stream>>>(gatedb, 512, Wsilb, 512, dbuf, 512, 512, nullptr, nullptr);
    redmax1_k<<<1024, 256, 0, stream>>>(dbuf, bmax, bidx);
    redmax2_k<<<1, 256, 0, stream>>>(bmax, bidx, 1024, &scal[0], &scalI[0]);
    ripple_g_k<<<2048, 256, 0, stream>>>(dbuf, Hbuf, sspart, &scal[0], p1a, p1b, p1m);
    redsum2_k<<<1, 256, 0, stream>>>(sspart, 2048, &scal[1]);
    ripple_softmax_k<1><<<16384, 256, 0, stream>>>(Hbuf, &scal[0], &scalI[0], &scal[1], p1a, gatedb, gsb);

    // ---- token selection -> sel ----
    ts1_k<<<4096, 256, 0, stream>>>(x, cls_w, cls_b, tokw, prelu, comb, vals);
    ts2_k<<<4, 256, 0, stream>>>(comb, vals, imp);
    ts3_k<<<1, 256, 0, stream>>>(imp, gmoe, sel, tsw, tsa, tsb, tsmix);

    // ---- attn = gs @ Woh^T, scaled by sel (d2 = attn*sel fused in epilogue) ----
    gemm_bt<3><<<dim3(4, 128), 256, 0, stream>>>(gsb, 512, Wohb, 512, dbuf, 512, 512, nullptr, sel);

    // ---- out_probs = ripple_act(d2) ----
    redmax1_k<<<1024, 256, 0, stream>>>(dbuf, bmax, bidx);
    redmax2_k<<<1, 256, 0, stream>>>(bmax, bidx, 1024, &scal[2], &scalI[1]);
    ripple_g_k<<<2048, 256, 0, stream>>>(dbuf, Hbuf, sspart, &scal[2], p2a, p2b, p2m);
    redsum2_k<<<1, 256, 0, stream>>>(sspart, 2048, &scal[3]);
    ripple_softmax_k<0><<<16384, 256, 0, stream>>>(Hbuf, &scal[2], &scalI[1], &scal[3], p2a, nullptr, probs2b);

    // ---- out = probs @ Wout^T ----
    gemm_bt<0><<<dim3(4, 128), 256, 0, stream>>>(probs2b, 512, Woutb, 512, out, 512, 512, nullptr, nullptr);
}

// Round 2
// 1017.389 us; speedup vs baseline: 4.0782x; 4.0782x over previous
//
#include <hip/hip_runtime.h>

typedef unsigned short ushort;
typedef unsigned int uint;

#define DEV __device__ __forceinline__

typedef __attribute__((ext_vector_type(4))) float f32x4;
typedef __bf16 bf16x8 __attribute__((ext_vector_type(8)));

static constexpr int B_ = 4, L_ = 4096, D_ = 512;
static constexpr long NE = (long)B_ * L_ * D_;      // 8388608
static constexpr int ROWS = B_ * L_;                // 16384

// ---------------- small helpers ----------------
DEV float b2f(ushort u) { return __uint_as_float(((uint)u) << 16); }
DEV ushort f2b(float f) {
    uint u = __float_as_uint(f);
    uint r = u + 0x7FFFu + ((u >> 16) & 1u);
    return (ushort)(r >> 16);
}
DEV uint mapF(float f) {
    uint b = __float_as_uint(f);
    return (b & 0x80000000u) ? ~b : (b | 0x80000000u);
}
DEV float unmapF(uint u) {
    uint b = (u & 0x80000000u) ? (u & 0x7FFFFFFFu) : ~u;
    return __uint_as_float(b);
}
DEV float sigm(float x) { return 1.f / (1.f + expf(-x)); }

// trigamma(t+1), t in (-1,1): psi1(x) = sum_{k=0..5} 1/(x+k)^2 + asym(x+6)
DEV float trigamma1p(float t) {
    float x = t + 1.f;
    float acc = 0.f;
#pragma unroll
    for (int k = 0; k < 6; k++) { float xx = x + (float)k; acc += 1.f / (xx * xx); }
    float y = x + 6.f;
    float iy = 1.f / y, iy2 = iy * iy;
    return acc + iy * (1.f + iy * (0.5f + iy * (0.166666667f + iy2 * (-0.0333333333f + iy2 * 0.0238095238f))));
}
// I1(t), |t|<~1.2: power series
DEV float besselI1(float t) {
    float q = 0.25f * t * t;
    return 0.5f * t * (1.f + q * (0.5f + q * (0.0833333333f + q * (0.00694444444f + q * (3.47222222e-4f + q * 1.15740741e-5f)))));
}
// Tprime = mix0*trigamma(t+1) + mix1*I1(t);  H = beta * Tprime * erf'(u)
DEV float rippleH(float u, float beta, float mix0, float mix1) {
    float t = beta * erff(u);
    float Tp = mix0 * trigamma1p(t) + mix1 * besselI1(t);
    float ep = 1.12837917f * expf(-u * u);
    return beta * Tp * ep;
}

// ---------------- GEMM: C[M,N] = A[M,K] * Bt[N,K]^T  (bf16 in, f32 accum) ----------------
// MODE 0: f32 out; 1: bf16 out; 2: atomic row-max into poolU (mapped uint); 3: f32 out scaled by rowScale[row]
template <int MODE>
__global__ __launch_bounds__(256, 2) void gemm_bt(
    const ushort* __restrict__ A, int lda,
    const ushort* __restrict__ Bt, int ldb,
    void* __restrict__ Cv, int ldc, int K,
    uint* __restrict__ poolU, const float* __restrict__ rowScale)
{
    __shared__ ushort Alds[128 * 32];
    __shared__ ushort Blds[128 * 32];
    const int tid = threadIdx.x;
    const int lane = tid & 63;
    const int wave = tid >> 6;
    const int wr = wave >> 1, wc = wave & 1;
    const int row0 = blockIdx.y * 128, col0 = blockIdx.x * 128;

    f32x4 acc[4][4] = {};

    const int r0c = tid >> 2;             // 0..63
    const int kc0 = (tid & 3) * 8;        // 0,8,16,24
    const ushort* Arow0 = A + (size_t)(row0 + r0c) * lda + kc0;
    const ushort* Arow1 = A + (size_t)(row0 + r0c + 64) * lda + kc0;
    const ushort* Brow0 = Bt + (size_t)(col0 + r0c) * ldb + kc0;
    const ushort* Brow1 = Bt + (size_t)(col0 + r0c + 64) * ldb + kc0;
    ushort* Asl0 = &Alds[r0c * 32 + kc0];
    ushort* Asl1 = &Alds[(r0c + 64) * 32 + kc0];
    ushort* Bsl0 = &Blds[r0c * 32 + kc0];
    ushort* Bsl1 = &Blds[(r0c + 64) * 32 + kc0];

    const int ar = wr * 64 + (lane & 15);
    const int br = wc * 64 + (lane & 15);
    const int kk = (lane >> 4) * 8;

    for (int k0 = 0; k0 < K; k0 += 32) {
        __syncthreads();
        *(bf16x8*)Asl0 = *(const bf16x8*)(Arow0 + k0);
        *(bf16x8*)Asl1 = *(const bf16x8*)(Arow1 + k0);
        *(bf16x8*)Bsl0 = *(const bf16x8*)(Brow0 + k0);
        *(bf16x8*)Bsl1 = *(const bf16x8*)(Brow1 + k0);
        __syncthreads();
        bf16x8 af[4], bfr[4];
#pragma unroll
        for (int mi = 0; mi < 4; mi++) af[mi] = *(const bf16x8*)&Alds[(ar + mi * 16) * 32 + kk];
#pragma unroll
        for (int ni = 0; ni < 4; ni++) bfr[ni] = *(const bf16x8*)&Blds[(br + ni * 16) * 32 + kk];
#pragma unroll
        for (int mi = 0; mi < 4; mi++)
#pragma unroll
            for (int ni = 0; ni < 4; ni++)
                acc[mi][ni] = __builtin_amdgcn_mfma_f32_16x16x32_bf16(af[mi], bfr[ni], acc[mi][ni], 0, 0, 0);
    }

    const int orow = row0 + wr * 64;
    const int ocol = col0 + wc * 64 + (lane & 15);
    if (MODE == 2) {
#pragma unroll
        for (int mi = 0; mi < 4; mi++) {
#pragma unroll
            for (int j = 0; j < 4; j++) {
                float v = acc[mi][0][j];
                v = fmaxf(v, acc[mi][1][j]); v = fmaxf(v, acc[mi][2][j]); v = fmaxf(v, acc[mi][3][j]);
#pragma unroll
                for (int off = 1; off < 16; off <<= 1) v = fmaxf(v, __shfl_xor(v, off));
                if ((lane & 15) == 0) {
                    int r = orow + mi * 16 + (lane >> 4) * 4 + j;
                    atomicMax(&poolU[r], mapF(v));
                }
            }
        }
    } else {
#pragma unroll
        for (int mi = 0; mi < 4; mi++) {
            const int rbase = orow + mi * 16 + (lane >> 4) * 4;
#pragma unroll
            for (int j = 0; j < 4; j++) {
                float sc = (MODE == 3) ? rowScale[rbase + j] : 1.f;
#pragma unroll
                for (int ni = 0; ni < 4; ni++) {
                    float v = acc[mi][ni][j] * sc;
                    int cc = ocol + ni * 16;
                    if (MODE == 1) ((ushort*)Cv)[(size_t)(rbase + j) * ldc + cc] = f2b(v);
                    else ((float*)Cv)[(size_t)(rbase + j) * ldc + cc] = v;
                }
            }
        }
    }
}

// ---------------- misc kernels ----------------
__global__ void convert_f2b_k(const float* __restrict__ s, ushort* __restrict__ d, long n) {
    long i = (long)blockIdx.x * blockDim.x + threadIdx.x;
    long st = (long)gridDim.x * blockDim.x;
    for (; i < n; i += st) d[i] = f2b(s[i]);
}

template <bool SRCF32>
__global__ __launch_bounds__(256) void transpose_to_bf16(const void* __restrict__ srcv, ushort* __restrict__ dst, int R, int C) {
    __shared__ float tile[32][33];
    const int z = blockIdx.z;
    const float* sf = (const float*)srcv + (size_t)z * R * C;
    const ushort* sb = (const ushort*)srcv + (size_t)z * R * C;
    ushort* dz = dst + (size_t)z * R * C;
    const int tx = threadIdx.x & 31, ty = threadIdx.x >> 5;
    const int c = blockIdx.x * 32 + tx;
#pragma unroll
    for (int k = 0; k < 4; k++) {
        const int r = blockIdx.y * 32 + ty + k * 8;
        tile[ty + k * 8][tx] = SRCF32 ? sf[(size_t)r * C + c] : b2f(sb[(size_t)r * C + c]);
    }
    __syncthreads();
#pragma unroll
    for (int k = 0; k < 4; k++) {
        const int dr = blockIdx.x * 32 + ty + k * 8;
        const int dc = blockIdx.y * 32 + tx;
        dz[(size_t)dr * R + dc] = f2b(tile[tx][ty + k * 8]);
    }
}

__global__ void init_pool_k(uint* poolU) {
    int i = blockIdx.x * 256 + threadIdx.x;
    if (i < 2048) poolU[i] = 0u;
}
__global__ void sentinel_k(float* o) { o[threadIdx.x] = 1.0e6f; }

// gates elementwise: nx = x*sigmoid(gxa)*sqrt(1-exp(2*la)); ea = exp(la); la = -8*softplus(a)*sigmoid(gaa)
__global__ void gates_elem_k(const float* __restrict__ x, const float* __restrict__ gxa, const float* __restrict__ gaa,
                             const float* __restrict__ a_param, ushort* __restrict__ nxb, ushort* __restrict__ eab) {
    long i = (long)blockIdx.x * blockDim.x + threadIdx.x;
    long st = (long)gridDim.x * blockDim.x;
    for (; i < NE; i += st) {
        int d = (int)(i & 511);
        float gx = sigm(gxa[i]);
        float ga = sigm(gaa[i]);
        float a = a_param[d];
        float sp = fmaxf(a, 0.f) + log1pf(expf(-fabsf(a)));
        float la = -8.f * sp * ga;
        float ea = expf(la);
        float nx = x[i] * gx * sqrtf(fmaxf(1.f - expf(2.f * la), 0.f));
        nxb[i] = f2b(nx);
        eab[i] = f2b(ea);
    }
}

// row softmax over N=4096 bf16 -> bf16 (for attention P)
__global__ __launch_bounds__(256) void softmax_rows_k(const ushort* __restrict__ S, ushort* __restrict__ P, float scale) {
    __shared__ float red[256];
    const int tid = threadIdx.x;
    const ushort* row = S + (size_t)blockIdx.x * 4096;
    float vals[16];
    bf16x8 v0 = *(const bf16x8*)&row[tid * 16];
    bf16x8 v1 = *(const bf16x8*)&row[tid * 16 + 8];
    float mx = -3.4e38f;
#pragma unroll
    for (int k = 0; k < 8; k++) { vals[k] = (float)v0[k] * scale; mx = fmaxf(mx, vals[k]); }
#pragma unroll
    for (int k = 0; k < 8; k++) { vals[8 + k] = (float)v1[k] * scale; mx = fmaxf(mx, vals[8 + k]); }
    red[tid] = mx; __syncthreads();
    for (int s = 128; s > 0; s >>= 1) { if (tid < s) red[tid] = fmaxf(red[tid], red[tid + s]); __syncthreads(); }
    mx = red[0]; __syncthreads();
    float sum = 0.f;
#pragma unroll
    for (int k = 0; k < 16; k++) { vals[k] = expf(vals[k] - mx); sum += vals[k]; }
    red[tid] = sum; __syncthreads();
    for (int s = 128; s > 0; s >>= 1) { if (tid < s) red[tid] += red[tid + s]; __syncthreads(); }
    float inv = 1.f / red[0];
    ushort* prow = P + (size_t)blockIdx.x * 4096;
#pragma unroll
    for (int k = 0; k < 16; k++) prow[tid * 16 + k] = f2b(vals[k] * inv);
}

// gated = ea*pool[b,d] + nx  (bf16 out)
__global__ void gated_k(const ushort* __restrict__ eab, const ushort* __restrict__ nxb,
                        const uint* __restrict__ poolU, ushort* __restrict__ gatedb) {
    long i = (long)blockIdx.x * blockDim.x + threadIdx.x;
    long st = (long)gridDim.x * blockDim.x;
    for (; i < NE; i += st) {
        int d = (int)(i & 511);
        int b = (int)(i >> 21);
        float pl = unmapF(poolU[b * 512 + d]);
        gatedb[i] = f2b(b2f(eab[i]) * pl + b2f(nxb[i]));
    }
}

// global max + argmax (stage1), n elements
__global__ __launch_bounds__(256) void redmax1_k(const float* __restrict__ d, long n, float* __restrict__ bmax, int* __restrict__ bidx) {
    __shared__ float rv[256];
    __shared__ int ri[256];
    const int tid = threadIdx.x;
    long g = (long)blockIdx.x * 256 + tid;
    const long stride = (long)gridDim.x * 256;
    float bv = -3.4e38f; int bi = -1;
    for (long i = g; i < n; i += stride) {
        float v = d[i];
        if (v > bv) { bv = v; bi = (int)i; }
    }
    rv[tid] = bv; ri[tid] = bi; __syncthreads();
    for (int s = 128; s > 0; s >>= 1) {
        if (tid < s) {
            float ov = rv[tid + s]; int oi = ri[tid + s];
            if (oi >= 0 && (ri[tid] < 0 || ov > rv[tid] || (ov == rv[tid] && oi < ri[tid]))) { rv[tid] = ov; ri[tid] = oi; }
        }
        __syncthreads();
    }
    if (tid == 0) { bmax[blockIdx.x] = rv[0]; bidx[blockIdx.x] = ri[0]; }
}
__global__ __launch_bounds__(256) void redmax2_k(const float* __restrict__ bmax, const int* __restrict__ bidx, int n,
                                                 float* __restrict__ outM, int* __restrict__ outI) {
    __shared__ float rv[256];
    __shared__ int ri[256];
    const int tid = threadIdx.x;
    float bv = -3.4e38f; int bi = -1;
    for (int i = tid; i < n; i += 256) {
        float v = bmax[i]; int ix = bidx[i];
        if (ix >= 0 && (bi < 0 || v > bv || (v == bv && ix < bi))) { bv = v; bi = ix; }
    }
    rv[tid] = bv; ri[tid] = bi; __syncthreads();
    for (int s = 128; s > 0; s >>= 1) {
        if (tid < s) {
            float ov = rv[tid + s]; int oi = ri[tid + s];
            if (oi >= 0 && (ri[tid] < 0 || ov > rv[tid] || (ov == rv[tid] && oi < ri[tid]))) { rv[tid] = ov; ri[tid] = oi; }
        }
        __syncthreads();
    }
    if (tid == 0) { outM[0] = rv[0]; outI[0] = ri[0]; }
}

// ripple gradient base: gb = beta*T'(t)*erf'(u)/(M*alpha); partial SS = sum beta*T'*erf'*d
__global__ __launch_bounds__(256) void ripple_g_k(const float* __restrict__ d, float* __restrict__ gb, float* __restrict__ sspart,
                                                  const float* __restrict__ scalM, const float* __restrict__ alpha_p,
                                                  const float* __restrict__ beta_p, const float* __restrict__ mix_p) {
    __shared__ float red[256];
    const int tid = threadIdx.x;
    const float M = scalM[0];
    const float alpha = alpha_p[0], beta = beta_p[0];
    float m0 = mix_p[0], m1 = mix_p[1];
    float mm = fmaxf(m0, m1);
    float e0 = expf(m0 - mm), e1 = expf(m1 - mm);
    float inv = 1.f / (e0 + e1);
    float mix0 = e0 * inv, mix1 = e1 * inv;
    const float invMA = 1.f / (M * alpha);
    float ss = 0.f;
    long g = (long)blockIdx.x * 256 + tid;
    const long stride = (long)gridDim.x * 256;
    for (long i = g; i < NE; i += stride) {
        float dv = d[i];
        float H = rippleH(dv * invMA, beta, mix0, mix1);
        gb[i] = H * invMA;
        ss += H * dv;
    }
    red[tid] = ss; __syncthreads();
    for (int s = 128; s > 0; s >>= 1) { if (tid < s) red[tid] += red[tid + s]; __syncthreads(); }
    if (tid == 0) sspart[blockIdx.x] = red[0];
}
__global__ __launch_bounds__(256) void redsum2_k(const float* __restrict__ part, int n, float* __restrict__ out) {
    __shared__ float red[256];
    const int tid = threadIdx.x;
    float s = 0.f;
    for (int i = tid; i < n; i += 256) s += part[i];
    red[tid] = s; __syncthreads();
    for (int q = 128; q > 0; q >>= 1) { if (tid < q) red[tid] += red[tid + q]; __syncthreads(); }
    if (tid == 0) out[0] = red[0];
}

// per-row (512) softmin: g = clip(gb - (i==amax)*SS/(M^2*alpha)); p = softmax(-g); out = bf16(p [* gated])
template <int GS>
__global__ __launch_bounds__(256) void ripple_softmax_k(const float* __restrict__ gb,
                                                        const float* __restrict__ scalM, const int* __restrict__ scalI,
                                                        const float* __restrict__ ssTot, const float* __restrict__ alpha_p,
                                                        const ushort* __restrict__ gatedb, ushort* __restrict__ outb) {
    __shared__ float red[256];
    const int tid = threadIdx.x;
    const float M = scalM[0];
    const int amax = scalI[0];
    const float corr = ssTot[0] / (M * M * alpha_p[0]);
    long base = (long)blockIdx.x * 512;
    float g0 = gb[base + tid];
    float g1 = gb[base + tid + 256];
    if ((int)(base + tid) == amax) g0 -= corr;
    if ((int)(base + tid + 256) == amax) g1 -= corr;
    g0 = fminf(fmaxf(g0, -1.f), 1.f);
    g1 = fminf(fmaxf(g1, -1.f), 1.f);
    float mn = fminf(g0, g1);
    red[tid] = mn; __syncthreads();
    for (int s = 128; s > 0; s >>= 1) { if (tid < s) red[tid] = fminf(red[tid], red[tid + s]); __syncthreads(); }
    mn = red[0]; __syncthreads();
    float e0 = expf(mn - g0), e1 = expf(mn - g1);
    red[tid] = e0 + e1; __syncthreads();
    for (int s = 128; s > 0; s >>= 1) { if (tid < s) red[tid] += red[tid + s]; __syncthreads(); }
    float inv = 1.f / red[0];
    if (GS) {
        outb[base + tid] = f2b(b2f(gatedb[base + tid]) * (e0 * inv));
        outb[base + tid + 256] = f2b(b2f(gatedb[base + tid + 256]) * (e1 * inv));
    } else {
        outb[base + tid] = f2b(e0 * inv);
        outb[base + tid + 256] = f2b(e1 * inv);
    }
}

// token selection stage 1: per row, scores for 4 heads -> combined, vals
__global__ __launch_bounds__(256) void ts1_k(const float* __restrict__ x, const float* __restrict__ cls_w,
                                             const float* __restrict__ cls_b, const float* __restrict__ tw,
                                             const float* __restrict__ prelu_a,
                                             float* __restrict__ combined, float* __restrict__ vals) {
    __shared__ float cw[2048];
    const int tid = threadIdx.x;
    for (int i = tid; i < 2048; i += 256) cw[i] = cls_w[i];
    __syncthreads();
    const int lane = tid & 63, wid = tid >> 6;
    const int row = blockIdx.x * 4 + wid;
    const float* xr = x + (size_t)row * 512 + lane * 8;
    float pa0 = 0, pa1 = 0, pa2 = 0, pa3 = 0;
#pragma unroll
    for (int j = 0; j < 8; j++) {
        float v = xr[j];
        int c = lane * 8 + j;
        pa0 += v * cw[c]; pa1 += v * cw[512 + c]; pa2 += v * cw[1024 + c]; pa3 += v * cw[1536 + c];
    }
#pragma unroll
    for (int o = 32; o > 0; o >>= 1) {
        pa0 += __shfl_down(pa0, o); pa1 += __shfl_down(pa1, o);
        pa2 += __shfl_down(pa2, o); pa3 += __shfl_down(pa3, o);
    }
    if (lane == 0) {
        float a = prelu_a[0];
        float sc[4] = {pa0, pa1, pa2, pa3};
        float comb = 0.f, vsum = 0.f;
#pragma unroll
        for (int s = 0; s < 4; s++) {
            float p = sc[s] + cls_b[s];
            p = (p >= 0.f) ? p : a * p;
            float cel = (p > 0.f) ? p : expm1f(p);
            float sil = p * sigm(p);
            float gel = 0.5f * p * (1.f + erff(p * 0.70710678f));
            float ts = cel * sil + gel;
            float ww = tw[s];
            float se = 1.05070099f * ((ww > 0.f) ? ww : 1.67326324f * expm1f(ww));
            comb += se * ts;
            vsum += ts;
        }
        combined[row] = comb;
        vals[row] = vsum;
    }
}

// token selection stage 2 (parallel): rank (stable descending) -> importance[p] = 1 + vals[rank(p)]
// grid: (L/256, B); one p per thread; whole row in LDS; q-loop broadcast-reads LDS.
__global__ __launch_bounds__(256) void ts2_k(const float* __restrict__ combined, const float* __restrict__ vals,
                                             float* __restrict__ imp) {
    __shared__ float c[4096];
    const int b = blockIdx.y;
    const int tid = threadIdx.x;
    const float* cr = combined + b * 4096;
    for (int i = tid; i < 4096; i += 256) c[i] = cr[i];
    __syncthreads();
    const int p = blockIdx.x * 256 + tid;
    const float cp = c[p];
    int rank = 0;
#pragma unroll 8
    for (int q = 0; q < 4096; q++) {
        float cq = c[q];
        rank += (cq > cp) || (cq == cp && q < p);
    }
    imp[b * 4096 + p] = 1.f + vals[b * 4096 + rank];
}

// moe gradient base over n=65536: gmoe[i] = sum_s w_s*H_s/(M*al_s); partial SS = sum_s w_s*H_s*d/al_s
__global__ __launch_bounds__(256) void moe_g_k(const float* __restrict__ imp, float* __restrict__ gmoe,
                                               float* __restrict__ sspart, const float* __restrict__ scalM,
                                               const float* __restrict__ tsw, const float* __restrict__ tsa,
                                               const float* __restrict__ tsb, const float* __restrict__ tsmix) {
    __shared__ float red[256];
    const int tid = threadIdx.x;
    const float M = scalM[0];
    float w[4];
    {
        float wm = fmaxf(fmaxf(tsw[0], tsw[1]), fmaxf(tsw[2], tsw[3]));
        float s = 0.f;
#pragma unroll
        for (int k = 0; k < 4; k++) { w[k] = expf(tsw[k] - wm); s += w[k]; }
#pragma unroll
        for (int k = 0; k < 4; k++) w[k] /= s;
    }
    const float beta = tsb[0];
    float m0 = tsmix[0], m1 = tsmix[1];
    float mm = fmaxf(m0, m1);
    float e0 = expf(m0 - mm), e1 = expf(m1 - mm);
    float minv = 1.f / (e0 + e1);
    const float mix0 = e0 * minv, mix1 = e1 * minv;

    float ss = 0.f;
    int i = blockIdx.x * 256 + tid;
    const int stride = gridDim.x * 256;
    for (; i < 65536; i += stride) {
        float dv = imp[i];
        float gbv = 0.f;
#pragma unroll
        for (int s = 0; s < 4; s++) {
            float al = tsa[s];
            float H = rippleH(dv / (M * al), beta, mix0, mix1);
            gbv += w[s] * H / (M * al);
            ss += w[s] * H * dv / al;
        }
        gmoe[i] = gbv;
    }
    red[tid] = ss; __syncthreads();
    for (int s = 128; s > 0; s >>= 1) { if (tid < s) red[tid] += red[tid + s]; __syncthreads(); }
    if (tid == 0) sspart[blockIdx.x] = red[0];
}

// moe softmin per batch row (4096): sel = 1 + softmax(-clip(g - amax_corr))
__global__ __launch_bounds__(256) void moe_sel_k(const float* __restrict__ gmoe, const float* __restrict__ scalM,
                                                 const int* __restrict__ scalI, const float* __restrict__ ssTot,
                                                 float* __restrict__ sel) {
    __shared__ float red[256];
    const int tid = threadIdx.x;
    const int b = blockIdx.x;
    const float M = scalM[0];
    const int amax = scalI[0];
    const float corr = ssTot[0] / (M * M);
    float g[16];
    float mn = 3.4e38f;
#pragma unroll
    for (int k = 0; k < 16; k++) {
        int i = b * 4096 + tid + k * 256;
        float v = gmoe[i];
        if (i == amax) v -= corr;
        v = fminf(fmaxf(v, -1.f), 1.f);
        g[k] = v;
        mn = fminf(mn, v);
    }
    red[tid] = mn; __syncthreads();
    for (int s = 128; s > 0; s >>= 1) { if (tid < s) red[tid] = fminf(red[tid], red[tid + s]); __syncthreads(); }
    mn = red[0]; __syncthreads();
    float sum = 0.f;
#pragma unroll
    for (int k = 0; k < 16; k++) { g[k] = expf(mn - g[k]); sum += g[k]; }
    red[tid] = sum; __syncthreads();
    for (int s = 128; s > 0; s >>= 1) { if (tid < s) red[tid] += red[tid + s]; __syncthreads(); }
    float inv = 1.f / red[0];
#pragma unroll
    for (int k = 0; k < 16; k++) sel[b * 4096 + tid + k * 256] = 1.f + g[k] * inv;
}

// ---------------- workspace layout (bytes) ----------------
static constexpr size_t OFF_XB    = 0;                       // ushort NE   (later: probs2b)
static constexpr size_t OFF_TMPB  = 16777216;                // ushort NE   (later: gsb)
static constexpr size_t OFF_SPB   = 33554432;                // ushort NE
static constexpr size_t OFF_SPT   = 50331648;                // ushort NE   ([4][512][4096])
static constexpr size_t OFF_DBUF  = 67108864;                // float NE    (gxa / Sb / d1 / attn)
static constexpr size_t OFF_HBUF  = 100663296;               // float NE    (gaa / P / H)
static constexpr size_t OFF_GATB  = 134217728;               // ushort NE
static constexpr size_t OFF_NXB   = 150994944;               // ushort NE
static constexpr size_t OFF_EAB   = 167772160;               // ushort NE
static constexpr size_t OFF_AST   = 184549376;               // 512*512 ushort
static constexpr size_t OFF_WSP   = 185073664;
static constexpr size_t OFF_WSIL  = 185597952;
static constexpr size_t OFF_WOH   = 186122240;
static constexpr size_t OFF_WOUT  = 186646528;
static constexpr size_t OFF_WIGT  = 187170816;               // 4*128*128 ushort
static constexpr size_t OFF_WAGT  = 187301888;
static constexpr size_t OFF_POOL  = 187432960;               // 2048 uint
static constexpr size_t OFF_SCAL  = 187441152;               // 64 float
static constexpr size_t OFF_SCALI = 187441408;               // 64 int
static constexpr size_t OFF_BMAX  = 187441664;               // 2048 float
static constexpr size_t OFF_BIDX  = 187449856;               // 2048 int
static constexpr size_t OFF_SSP   = 187458048;               // 2048 float
static constexpr size_t OFF_COMB  = 187466240;               // 65536 float
static constexpr size_t OFF_VALS  = 187728384;
static constexpr size_t OFF_IMP   = 187990528;
static constexpr size_t OFF_GMOE  = 188252672;
static constexpr size_t OFF_SEL   = 188514816;
static constexpr size_t WS_NEED   = 188776960;

extern "C" void kernel_launch(void* const* d_in, const int* in_sizes, int n_in,
                              void* d_out, int out_size, void* d_ws, size_t ws_size,
                              hipStream_t stream)
{
    (void)in_sizes; (void)n_in; (void)out_size;
    const float* x    = (const float*)d_in[0];
    const float* AS   = (const float*)d_in[1];
    const float* Wsp  = (const float*)d_in[2];
    const float* Wsil = (const float*)d_in[3];
    const float* Woh  = (const float*)d_in[4];
    const float* Wout = (const float*)d_in[5];
    const float* wig  = (const float*)d_in[6];
    const float* wag  = (const float*)d_in[7];
    const float* a_param = (const float*)d_in[8];
    const float* cls_w = (const float*)d_in[9];
    const float* cls_b = (const float*)d_in[10];
    const float* tokw  = (const float*)d_in[11];
    const float* prelu = (const float*)d_in[12];
    const float* tsw   = (const float*)d_in[13];
    const float* tsa   = (const float*)d_in[14];
    const float* tsb   = (const float*)d_in[15];
    const float* tsmix = (const float*)d_in[16];
    const float* p1a = (const float*)d_in[17];
    const float* p1b = (const float*)d_in[18];
    const float* p1m = (const float*)d_in[19];
    const float* p2a = (const float*)d_in[20];
    const float* p2b = (const float*)d_in[21];
    const float* p2m = (const float*)d_in[22];
    float* out = (float*)d_out;

    char* w = (char*)d_ws;
    if (ws_size < WS_NEED) { sentinel_k<<<1, 256, 0, stream>>>(out); return; }

    ushort* xb    = (ushort*)(w + OFF_XB);
    ushort* tmpb  = (ushort*)(w + OFF_TMPB);
    ushort* spb   = (ushort*)(w + OFF_SPB);
    ushort* spT   = (ushort*)(w + OFF_SPT);
    float*  dbuf  = (float*)(w + OFF_DBUF);
    float*  Hbuf  = (float*)(w + OFF_HBUF);
    ushort* Sb    = (ushort*)(w + OFF_DBUF);   // alias
    ushort* Pb    = (ushort*)(w + OFF_HBUF);   // alias
    float*  gxa   = (float*)(w + OFF_DBUF);    // alias
    float*  gaa   = (float*)(w + OFF_HBUF);    // alias
    ushort* gatedb= (ushort*)(w + OFF_GATB);
    ushort* nxb   = (ushort*)(w + OFF_NXB);
    ushort* eab   = (ushort*)(w + OFF_EAB);
    ushort* ASt   = (ushort*)(w + OFF_AST);
    ushort* Wspb  = (ushort*)(w + OFF_WSP);
    ushort* Wsilb = (ushort*)(w + OFF_WSIL);
    ushort* Wohb  = (ushort*)(w + OFF_WOH);
    ushort* Woutb = (ushort*)(w + OFF_WOUT);
    ushort* wigT  = (ushort*)(w + OFF_WIGT);
    ushort* wagT  = (ushort*)(w + OFF_WAGT);
    uint*   poolU = (uint*)(w + OFF_POOL);
    float*  scal  = (float*)(w + OFF_SCAL);
    int*    scalI = (int*)(w + OFF_SCALI);
    float*  bmax  = (float*)(w + OFF_BMAX);
    int*    bidx  = (int*)(w + OFF_BIDX);
    float*  sspart= (float*)(w + OFF_SSP);
    float*  comb  = (float*)(w + OFF_COMB);
    float*  vals  = (float*)(w + OFF_VALS);
    float*  imp   = (float*)(w + OFF_IMP);
    float*  gmoe  = (float*)(w + OFF_GMOE);
    float*  sel   = (float*)(w + OFF_SEL);
    ushort* gsb     = tmpb;   // reuse
    ushort* probs2b = xb;     // reuse

    // ---- prep ----
    convert_f2b_k<<<4096, 256, 0, stream>>>(x, xb, NE);
    convert_f2b_k<<<256, 256, 0, stream>>>(Wsp, Wspb, 262144);
    convert_f2b_k<<<256, 256, 0, stream>>>(Wsil, Wsilb, 262144);
    convert_f2b_k<<<256, 256, 0, stream>>>(Woh, Wohb, 262144);
    convert_f2b_k<<<256, 256, 0, stream>>>(Wout, Woutb, 262144);
    transpose_to_bf16<true><<<dim3(16, 16, 1), 256, 0, stream>>>(AS, ASt, 512, 512);
    transpose_to_bf16<true><<<dim3(4, 4, 4), 256, 0, stream>>>(wig, wigT, 128, 128);
    transpose_to_bf16<true><<<dim3(4, 4, 4), 256, 0, stream>>>(wag, wagT, 128, 128);
    init_pool_k<<<8, 256, 0, stream>>>(poolU);

    // ---- G1: tmp = x @ AS ; G2: spatial = tmp @ Wsp^T ----
    gemm_bt<1><<<dim3(4, 128), 256, 0, stream>>>(xb, 512, ASt, 512, tmpb, 512, 512, nullptr, nullptr);
    gemm_bt<1><<<dim3(4, 128), 256, 0, stream>>>(tmpb, 512, Wspb, 512, spb, 512, 512, nullptr, nullptr);

    // ---- gates: block-diag GEMMs then elementwise ----
    for (int h = 0; h < 4; h++) {
        gemm_bt<0><<<dim3(1, 128), 256, 0, stream>>>(xb + h * 128, 512, wigT + h * 16384, 128, gxa + h * 128, 512, 128, nullptr, nullptr);
        gemm_bt<0><<<dim3(1, 128), 256, 0, stream>>>(xb + h * 128, 512, wagT + h * 16384, 128, gaa + h * 128, 512, 128, nullptr, nullptr);
    }
    gates_elem_k<<<4096, 256, 0, stream>>>(x, gxa, gaa, a_param, nxb, eab);

    // ---- attention pool (per batch): S = sp sp^T ; P = softmax(S/sqrt(128)) ; pool = rowmax(spT P^T) ----
    transpose_to_bf16<false><<<dim3(16, 128, 4), 256, 0, stream>>>(spb, spT, 4096, 512);
    const float sc128 = 0.0883883476f;
    for (int b = 0; b < 4; b++) {
        const ushort* spB = spb + (size_t)b * L_ * D_;
        gemm_bt<1><<<dim3(32, 32), 256, 0, stream>>>(spB, 512, spB, 512, Sb, 4096, 512, nullptr, nullptr);
        softmax_rows_k<<<4096, 256, 0, stream>>>(Sb, Pb, sc128);
        gemm_bt<2><<<dim3(32, 4), 256, 0, stream>>>(spT + (size_t)b * D_ * L_, 4096, Pb, 4096, nullptr, 0, 4096, poolU + b * 512, nullptr);
    }

    // ---- gated = exp(log_a)*pool + nx ----
    gated_k<<<4096, 256, 0, stream>>>(eab, nxb, poolU, gatedb);

    // ---- sparsity = ripple_act(gated @ Wsil^T) ; gs = gated * sparsity ----
    gemm_bt<0><<<dim3(4, 128), 256, 0, stream>>>(gatedb, 512, Wsilb, 512, dbuf, 512, 512, nullptr, nullptr);
    redmax1_k<<<1024, 256, 0, stream>>>(dbuf, NE, bmax, bidx);
    redmax2_k<<<1, 256, 0, stream>>>(bmax, bidx, 1024, &scal[0], &scalI[0]);
    ripple_g_k<<<2048, 256, 0, stream>>>(dbuf, Hbuf, sspart, &scal[0], p1a, p1b, p1m);
    redsum2_k<<<1, 256, 0, stream>>>(sspart, 2048, &scal[1]);
    ripple_softmax_k<1><<<16384, 256, 0, stream>>>(Hbuf, &scal[0], &scalI[0], &scal[1], p1a, gatedb, gsb);

    // ---- token selection -> sel ----
    ts1_k<<<4096, 256, 0, stream>>>(x, cls_w, cls_b, tokw, prelu, comb, vals);
    ts2_k<<<dim3(16, 4), 256, 0, stream>>>(comb, vals, imp);
    redmax1_k<<<64, 256, 0, stream>>>(imp, 65536, bmax, bidx);
    redmax2_k<<<1, 256, 0, stream>>>(bmax, bidx, 64, &scal[4], &scalI[2]);
    moe_g_k<<<64, 256, 0, stream>>>(imp, gmoe, sspart, &scal[4], tsw, tsa, tsb, tsmix);
    redsum2_k<<<1, 256, 0, stream>>>(sspart, 64, &scal[5]);
    moe_sel_k<<<4, 256, 0, stream>>>(gmoe, &scal[4], &scalI[2], &scal[5], sel);

    // ---- attn = gs @ Woh^T, scaled by sel (d2 = attn*sel fused in epilogue) ----
    gemm_bt<3><<<dim3(4, 128), 256, 0, stream>>>(gsb, 512, Wohb, 512, dbuf, 512, 512, nullptr, sel);

    // ---- out_probs = ripple_act(d2) ----
    redmax1_k<<<1024, 256, 0, stream>>>(dbuf, NE, bmax, bidx);
    redmax2_k<<<1, 256, 0, stream>>>(bmax, bidx, 1024, &scal[2], &scalI[1]);
    ripple_g_k<<<2048, 256, 0, stream>>>(dbuf, Hbuf, sspart, &scal[2], p2a, p2b, p2m);
    redsum2_k<<<1, 256, 0, stream>>>(sspart, 2048, &scal[3]);
    ripple_softmax_k<0><<<16384, 256, 0, stream>>>(Hbuf, &scal[2], &scalI[1], &scal[3], p2a, nullptr, probs2b);

    // ---- out = probs @ Wout^T ----
    gemm_bt<0><<<dim3(4, 128), 256, 0, stream>>>(probs2b, 512, Woutb, 512, out, 512, 512, nullptr, nullptr);
}

// Round 3
// 856.442 us; speedup vs baseline: 4.8446x; 1.1879x over previous
//
#include <hip/hip_runtime.h>

typedef unsigned short ushort;
typedef unsigned int uint;

#define DEV __device__ __forceinline__

typedef __attribute__((ext_vector_type(4))) float f32x4;
typedef __bf16 bf16x8 __attribute__((ext_vector_type(8)));
typedef __attribute__((ext_vector_type(4))) ushort u16x4;
typedef __attribute__((ext_vector_type(8))) ushort u16x8;

static constexpr int B_ = 4, L_ = 4096, D_ = 512;
static constexpr long NE = (long)B_ * L_ * D_;      // 8388608
static constexpr int ROWS = B_ * L_;                // 16384

// ---------------- small helpers ----------------
DEV float b2f(ushort u) { return __uint_as_float(((uint)u) << 16); }
DEV ushort f2b(float f) {
    uint u = __float_as_uint(f);
    uint r = u + 0x7FFFu + ((u >> 16) & 1u);
    return (ushort)(r >> 16);
}
DEV uint mapF(float f) {
    uint b = __float_as_uint(f);
    return (b & 0x80000000u) ? ~b : (b | 0x80000000u);
}
DEV float unmapF(uint u) {
    uint b = (u & 0x80000000u) ? (u & 0x7FFFFFFFu) : ~u;
    return __uint_as_float(b);
}
DEV float sigm(float x) { return 1.f / (1.f + expf(-x)); }

// trigamma(t+1), t in (-1,1)
DEV float trigamma1p(float t) {
    float x = t + 1.f;
    float acc = 0.f;
#pragma unroll
    for (int k = 0; k < 6; k++) { float xx = x + (float)k; acc += 1.f / (xx * xx); }
    float y = x + 6.f;
    float iy = 1.f / y, iy2 = iy * iy;
    return acc + iy * (1.f + iy * (0.5f + iy * (0.166666667f + iy2 * (-0.0333333333f + iy2 * 0.0238095238f))));
}
// I1(t), |t|<~1.2: power series
DEV float besselI1(float t) {
    float q = 0.25f * t * t;
    return 0.5f * t * (1.f + q * (0.5f + q * (0.0833333333f + q * (0.00694444444f + q * (3.47222222e-4f + q * 1.15740741e-5f)))));
}
DEV float rippleH(float u, float beta, float mix0, float mix1) {
    float t = beta * erff(u);
    float Tp = mix0 * trigamma1p(t) + mix1 * besselI1(t);
    float ep = 1.12837917f * expf(-u * u);
    return beta * Tp * ep;
}

// ---------------- shared GEMM core: 128x128 tile, K-loop, bf16 MFMA ----------------
// A pre-offset to tile row 0 (lda elems/row); Bt pre-offset to tile col 0 (ldb elems/row).
DEV void gemm_core(const ushort* __restrict__ A, int lda,
                   const ushort* __restrict__ Bt, int ldb, int K,
                   ushort* __restrict__ Alds, ushort* __restrict__ Blds,
                   f32x4 (&acc)[4][4])
{
    const int tid = threadIdx.x;
    const int lane = tid & 63;
    const int wave = tid >> 6;
    const int wr = wave >> 1, wc = wave & 1;

    const int r0c = tid >> 2;             // 0..63
    const int kc0 = (tid & 3) * 8;        // 0,8,16,24
    const ushort* Arow0 = A + (size_t)r0c * lda + kc0;
    const ushort* Arow1 = A + (size_t)(r0c + 64) * lda + kc0;
    const ushort* Brow0 = Bt + (size_t)r0c * ldb + kc0;
    const ushort* Brow1 = Bt + (size_t)(r0c + 64) * ldb + kc0;
    ushort* Asl0 = &Alds[r0c * 32 + kc0];
    ushort* Asl1 = &Alds[(r0c + 64) * 32 + kc0];
    ushort* Bsl0 = &Blds[r0c * 32 + kc0];
    ushort* Bsl1 = &Blds[(r0c + 64) * 32 + kc0];

    const int ar = wr * 64 + (lane & 15);
    const int br = wc * 64 + (lane & 15);
    const int kk = (lane >> 4) * 8;

    for (int k0 = 0; k0 < K; k0 += 32) {
        __syncthreads();
        *(bf16x8*)Asl0 = *(const bf16x8*)(Arow0 + k0);
        *(bf16x8*)Asl1 = *(const bf16x8*)(Arow1 + k0);
        *(bf16x8*)Bsl0 = *(const bf16x8*)(Brow0 + k0);
        *(bf16x8*)Bsl1 = *(const bf16x8*)(Brow1 + k0);
        __syncthreads();
        bf16x8 af[4], bfr[4];
#pragma unroll
        for (int mi = 0; mi < 4; mi++) af[mi] = *(const bf16x8*)&Alds[(ar + mi * 16) * 32 + kk];
#pragma unroll
        for (int ni = 0; ni < 4; ni++) bfr[ni] = *(const bf16x8*)&Blds[(br + ni * 16) * 32 + kk];
#pragma unroll
        for (int mi = 0; mi < 4; mi++)
#pragma unroll
            for (int ni = 0; ni < 4; ni++)
                acc[mi][ni] = __builtin_amdgcn_mfma_f32_16x16x32_bf16(af[mi], bfr[ni], acc[mi][ni], 0, 0, 0);
    }
}

// ---------------- GEMM: C[M,N] = A[M,K] * Bt[N,K]^T ----------------
// MODE 0: f32 out; 1: bf16 out; 3: f32 out scaled by rowScale[global row]
template <int MODE>
__global__ __launch_bounds__(256, 2) void gemm_bt(
    const ushort* __restrict__ A, int lda,
    const ushort* __restrict__ Bt, int ldb,
    void* __restrict__ Cv, int ldc, int K,
    const float* __restrict__ rowScale)
{
    __shared__ ushort Alds[128 * 32];
    __shared__ ushort Blds[128 * 32];
    const int row0 = blockIdx.y * 128, col0 = blockIdx.x * 128;
    f32x4 acc[4][4] = {};
    gemm_core(A + (size_t)row0 * lda, lda, Bt + (size_t)col0 * ldb, ldb, K, Alds, Blds, acc);

    const int tid = threadIdx.x;
    const int lane = tid & 63;
    const int wave = tid >> 6;
    const int wr = wave >> 1, wc = wave & 1;
    const int ocol = col0 + wc * 64 + (lane & 15);
#pragma unroll
    for (int mi = 0; mi < 4; mi++) {
        const int rbase = row0 + wr * 64 + mi * 16 + (lane >> 4) * 4;
#pragma unroll
        for (int j = 0; j < 4; j++) {
            float sc = (MODE == 3) ? rowScale[rbase + j] : 1.f;
#pragma unroll
            for (int ni = 0; ni < 4; ni++) {
                float v = acc[mi][ni][j] * sc;
                int cc = ocol + ni * 16;
                if (MODE == 1) ((ushort*)Cv)[(size_t)(rbase + j) * ldc + cc] = f2b(v);
                else ((float*)Cv)[(size_t)(rbase + j) * ldc + cc] = v;
            }
        }
    }
}

// ---------------- PV split-K: part[ks][4096][512] = P[:, ks*1024:(ks+1)*1024] @ V ----------------
__global__ __launch_bounds__(256, 2) void pv_split_k(const ushort* __restrict__ P, const ushort* __restrict__ Vt,
                                                     float* __restrict__ part)
{
    __shared__ ushort Alds[128 * 32];
    __shared__ ushort Blds[128 * 32];
    const int ks = blockIdx.z;
    const int row0 = blockIdx.y * 128, col0 = blockIdx.x * 128;
    f32x4 acc[4][4] = {};
    gemm_core(P + (size_t)row0 * 4096 + ks * 1024, 4096,
              Vt + (size_t)col0 * 4096 + ks * 1024, 4096, 1024, Alds, Blds, acc);

    float* C = part + (size_t)ks * 2097152 + (size_t)row0 * 512 + col0;
    const int tid = threadIdx.x;
    const int lane = tid & 63;
    const int wave = tid >> 6;
    const int wr = wave >> 1, wc = wave & 1;
    const int ocol = wc * 64 + (lane & 15);
#pragma unroll
    for (int mi = 0; mi < 4; mi++) {
        const int rl = wr * 64 + mi * 16 + (lane >> 4) * 4;
#pragma unroll
        for (int j = 0; j < 4; j++)
#pragma unroll
            for (int ni = 0; ni < 4; ni++)
                C[(size_t)(rl + j) * 512 + ocol + ni * 16] = acc[mi][ni][j];
    }
}

// combine: pool[d] = max over l of sum_ks part[ks][l][d]; 128 blocks x 32 rows
__global__ __launch_bounds__(256) void pool_combine_k(const float* __restrict__ part, uint* __restrict__ poolU)
{
    const int tid = threadIdx.x;
    const int l0 = blockIdx.x * 32;
    float m0 = -3.4e38f, m1 = -3.4e38f;
    for (int l = 0; l < 32; l++) {
        size_t off = (size_t)(l0 + l) * 512;
        float s0 = 0.f, s1 = 0.f;
#pragma unroll
        for (int ks = 0; ks < 4; ks++) {
            s0 += part[(size_t)ks * 2097152 + off + tid];
            s1 += part[(size_t)ks * 2097152 + off + tid + 256];
        }
        m0 = fmaxf(m0, s0); m1 = fmaxf(m1, s1);
    }
    atomicMax(&poolU[tid], mapF(m0));
    atomicMax(&poolU[tid + 256], mapF(m1));
}

// ---------------- batched block-diag gate GEMMs: grid (2, 128, 4) ----------------
__global__ __launch_bounds__(256, 2) void gate_gemm_k(const ushort* __restrict__ xb,
                                                      const ushort* __restrict__ wigT, const ushort* __restrict__ wagT,
                                                      float* __restrict__ gxa, float* __restrict__ gaa)
{
    __shared__ ushort Alds[128 * 32];
    __shared__ ushort Blds[128 * 32];
    const int which = blockIdx.x;
    const int h = blockIdx.z;
    const ushort* A = xb + (size_t)blockIdx.y * 128 * 512 + h * 128;
    const ushort* W = (which ? wagT : wigT) + (size_t)h * 16384;
    f32x4 acc[4][4] = {};
    gemm_core(A, 512, W, 128, 128, Alds, Blds, acc);

    float* C = (which ? gaa : gxa) + (size_t)blockIdx.y * 128 * 512 + h * 128;
    const int tid = threadIdx.x;
    const int lane = tid & 63;
    const int wave = tid >> 6;
    const int wr = wave >> 1, wc = wave & 1;
    const int ocol = wc * 64 + (lane & 15);
#pragma unroll
    for (int mi = 0; mi < 4; mi++) {
        const int rl = wr * 64 + mi * 16 + (lane >> 4) * 4;
#pragma unroll
        for (int j = 0; j < 4; j++)
#pragma unroll
            for (int ni = 0; ni < 4; ni++)
                C[(size_t)(rl + j) * 512 + ocol + ni * 16] = acc[mi][ni][j];
    }
}

// ---------------- misc kernels ----------------
__global__ void convert_f2b_k(const float* __restrict__ s, ushort* __restrict__ d, long n4) {
    long i = (long)blockIdx.x * blockDim.x + threadIdx.x;
    long st = (long)gridDim.x * blockDim.x;
    for (; i < n4; i += st) {
        f32x4 v = ((const f32x4*)s)[i];
        u16x4 o;
        o[0] = f2b(v[0]); o[1] = f2b(v[1]); o[2] = f2b(v[2]); o[3] = f2b(v[3]);
        ((u16x4*)d)[i] = o;
    }
}

template <bool SRCF32>
__global__ __launch_bounds__(256) void transpose_to_bf16(const void* __restrict__ srcv, ushort* __restrict__ dst, int R, int C) {
    __shared__ float tile[32][33];
    const int z = blockIdx.z;
    const float* sf = (const float*)srcv + (size_t)z * R * C;
    const ushort* sb = (const ushort*)srcv + (size_t)z * R * C;
    ushort* dz = dst + (size_t)z * R * C;
    const int tx = threadIdx.x & 31, ty = threadIdx.x >> 5;
    const int c = blockIdx.x * 32 + tx;
#pragma unroll
    for (int k = 0; k < 4; k++) {
        const int r = blockIdx.y * 32 + ty + k * 8;
        tile[ty + k * 8][tx] = SRCF32 ? sf[(size_t)r * C + c] : b2f(sb[(size_t)r * C + c]);
    }
    __syncthreads();
#pragma unroll
    for (int k = 0; k < 4; k++) {
        const int dr = blockIdx.x * 32 + ty + k * 8;
        const int dc = blockIdx.y * 32 + tx;
        dz[(size_t)dr * R + dc] = f2b(tile[tx][ty + k * 8]);
    }
}

__global__ void init_pool_k(uint* poolU) {
    int i = blockIdx.x * 256 + threadIdx.x;
    if (i < 2048) poolU[i] = 0u;
}
__global__ void sentinel_k(float* o) { o[threadIdx.x] = 1.0e6f; }

// gates elementwise (x4 vectorized)
__global__ __launch_bounds__(256) void gates_elem_k(const float* __restrict__ x, const float* __restrict__ gxa,
                                                    const float* __restrict__ gaa, const float* __restrict__ a_param,
                                                    ushort* __restrict__ nxb, ushort* __restrict__ eab) {
    __shared__ float sp8[512];
    const int tid = threadIdx.x;
    for (int d = tid; d < 512; d += 256) {
        float a = a_param[d];
        sp8[d] = 8.f * (fmaxf(a, 0.f) + log1pf(expf(-fabsf(a))));
    }
    __syncthreads();
    long i = (long)blockIdx.x * blockDim.x + tid;
    long st = (long)gridDim.x * blockDim.x;
    const long n4 = NE >> 2;
    for (; i < n4; i += st) {
        f32x4 xv = ((const f32x4*)x)[i];
        f32x4 gx4 = ((const f32x4*)gxa)[i];
        f32x4 ga4 = ((const f32x4*)gaa)[i];
        u16x4 nx4, ea4;
        long e = i << 2;
#pragma unroll
        for (int j = 0; j < 4; j++) {
            int d = (int)((e + j) & 511);
            float la = -sp8[d] * sigm(ga4[j]);
            float ea = expf(la);
            float nx = xv[j] * sigm(gx4[j]) * sqrtf(fmaxf(1.f - expf(2.f * la), 0.f));
            nx4[j] = f2b(nx);
            ea4[j] = f2b(ea);
        }
        ((u16x4*)nxb)[i] = nx4;
        ((u16x4*)eab)[i] = ea4;
    }
}

// row softmax over N=4096 bf16 -> bf16
__global__ __launch_bounds__(256) void softmax_rows_k(const ushort* __restrict__ S, ushort* __restrict__ P, float scale) {
    __shared__ float red[256];
    const int tid = threadIdx.x;
    const ushort* row = S + (size_t)blockIdx.x * 4096;
    float vals[16];
    bf16x8 v0 = *(const bf16x8*)&row[tid * 16];
    bf16x8 v1 = *(const bf16x8*)&row[tid * 16 + 8];
    float mx = -3.4e38f;
#pragma unroll
    for (int k = 0; k < 8; k++) { vals[k] = (float)v0[k] * scale; mx = fmaxf(mx, vals[k]); }
#pragma unroll
    for (int k = 0; k < 8; k++) { vals[8 + k] = (float)v1[k] * scale; mx = fmaxf(mx, vals[8 + k]); }
    red[tid] = mx; __syncthreads();
    for (int s = 128; s > 0; s >>= 1) { if (tid < s) red[tid] = fmaxf(red[tid], red[tid + s]); __syncthreads(); }
    mx = red[0]; __syncthreads();
    float sum = 0.f;
#pragma unroll
    for (int k = 0; k < 16; k++) { vals[k] = expf(vals[k] - mx); sum += vals[k]; }
    red[tid] = sum; __syncthreads();
    for (int s = 128; s > 0; s >>= 1) { if (tid < s) red[tid] += red[tid + s]; __syncthreads(); }
    float inv = 1.f / red[0];
    ushort* prow = P + (size_t)blockIdx.x * 4096;
#pragma unroll
    for (int k = 0; k < 16; k++) prow[tid * 16 + k] = f2b(vals[k] * inv);
}

// gated = ea*pool[b,d] + nx  (x8 vectorized)
__global__ __launch_bounds__(256) void gated_k(const ushort* __restrict__ eab, const ushort* __restrict__ nxb,
                                               const uint* __restrict__ poolU, ushort* __restrict__ gatedb) {
    long i = (long)blockIdx.x * blockDim.x + threadIdx.x;
    long st = (long)gridDim.x * blockDim.x;
    const long n8 = NE >> 3;
    for (; i < n8; i += st) {
        u16x8 ea8 = ((const u16x8*)eab)[i];
        u16x8 nx8 = ((const u16x8*)nxb)[i];
        u16x8 o;
        long e = i << 3;
        int b = (int)(e >> 21);
        int d0 = (int)(e & 511);
#pragma unroll
        for (int j = 0; j < 8; j++) {
            float pl = unmapF(poolU[b * 512 + d0 + j]);
            o[j] = f2b(b2f(ea8[j]) * pl + b2f(nx8[j]));
        }
        ((u16x8*)gatedb)[i] = o;
    }
}

// global max + argmax (stage1), n elements
__global__ __launch_bounds__(256) void redmax1_k(const float* __restrict__ d, long n, float* __restrict__ bmax, int* __restrict__ bidx) {
    __shared__ float rv[256];
    __shared__ int ri[256];
    const int tid = threadIdx.x;
    long g = (long)blockIdx.x * 256 + tid;
    const long stride = (long)gridDim.x * 256;
    float bv = -3.4e38f; int bi = -1;
    for (long i = g; i < n; i += stride) {
        float v = d[i];
        if (v > bv) { bv = v; bi = (int)i; }
    }
    rv[tid] = bv; ri[tid] = bi; __syncthreads();
    for (int s = 128; s > 0; s >>= 1) {
        if (tid < s) {
            float ov = rv[tid + s]; int oi = ri[tid + s];
            if (oi >= 0 && (ri[tid] < 0 || ov > rv[tid] || (ov == rv[tid] && oi < ri[tid]))) { rv[tid] = ov; ri[tid] = oi; }
        }
        __syncthreads();
    }
    if (tid == 0) { bmax[blockIdx.x] = rv[0]; bidx[blockIdx.x] = ri[0]; }
}
__global__ __launch_bounds__(256) void redmax2_k(const float* __restrict__ bmax, const int* __restrict__ bidx, int n,
                                                 float* __restrict__ outM, int* __restrict__ outI) {
    __shared__ float rv[256];
    __shared__ int ri[256];
    const int tid = threadIdx.x;
    float bv = -3.4e38f; int bi = -1;
    for (int i = tid; i < n; i += 256) {
        float v = bmax[i]; int ix = bidx[i];
        if (ix >= 0 && (bi < 0 || v > bv || (v == bv && ix < bi))) { bv = v; bi = ix; }
    }
    rv[tid] = bv; ri[tid] = bi; __syncthreads();
    for (int s = 128; s > 0; s >>= 1) {
        if (tid < s) {
            float ov = rv[tid + s]; int oi = ri[tid + s];
            if (oi >= 0 && (ri[tid] < 0 || ov > rv[tid] || (ov == rv[tid] && oi < ri[tid]))) { rv[tid] = ov; ri[tid] = oi; }
        }
        __syncthreads();
    }
    if (tid == 0) { outM[0] = rv[0]; outI[0] = ri[0]; }
}

// ripple gradient base
__global__ __launch_bounds__(256) void ripple_g_k(const float* __restrict__ d, float* __restrict__ gb, float* __restrict__ sspart,
                                                  const float* __restrict__ scalM, const float* __restrict__ alpha_p,
                                                  const float* __restrict__ beta_p, const float* __restrict__ mix_p) {
    __shared__ float red[256];
    const int tid = threadIdx.x;
    const float M = scalM[0];
    const float alpha = alpha_p[0], beta = beta_p[0];
    float m0 = mix_p[0], m1 = mix_p[1];
    float mm = fmaxf(m0, m1);
    float e0 = expf(m0 - mm), e1 = expf(m1 - mm);
    float inv = 1.f / (e0 + e1);
    float mix0 = e0 * inv, mix1 = e1 * inv;
    const float invMA = 1.f / (M * alpha);
    float ss = 0.f;
    long g = (long)blockIdx.x * 256 + tid;
    const long stride = (long)gridDim.x * 256;
    for (long i = g; i < NE; i += stride) {
        float dv = d[i];
        float H = rippleH(dv * invMA, beta, mix0, mix1);
        gb[i] = H * invMA;
        ss += H * dv;
    }
    red[tid] = ss; __syncthreads();
    for (int s = 128; s > 0; s >>= 1) { if (tid < s) red[tid] += red[tid + s]; __syncthreads(); }
    if (tid == 0) sspart[blockIdx.x] = red[0];
}
__global__ __launch_bounds__(256) void redsum2_k(const float* __restrict__ part, int n, float* __restrict__ out) {
    __shared__ float red[256];
    const int tid = threadIdx.x;
    float s = 0.f;
    for (int i = tid; i < n; i += 256) s += part[i];
    red[tid] = s; __syncthreads();
    for (int q = 128; q > 0; q >>= 1) { if (tid < q) red[tid] += red[tid + q]; __syncthreads(); }
    if (tid == 0) out[0] = red[0];
}

// per-row (512) softmin
template <int GS>
__global__ __launch_bounds__(256) void ripple_softmax_k(const float* __restrict__ gb,
                                                        const float* __restrict__ scalM, const int* __restrict__ scalI,
                                                        const float* __restrict__ ssTot, const float* __restrict__ alpha_p,
                                                        const ushort* __restrict__ gatedb, ushort* __restrict__ outb) {
    __shared__ float red[256];
    const int tid = threadIdx.x;
    const float M = scalM[0];
    const int amax = scalI[0];
    const float corr = ssTot[0] / (M * M * alpha_p[0]);
    long base = (long)blockIdx.x * 512;
    float g0 = gb[base + tid];
    float g1 = gb[base + tid + 256];
    if ((int)(base + tid) == amax) g0 -= corr;
    if ((int)(base + tid + 256) == amax) g1 -= corr;
    g0 = fminf(fmaxf(g0, -1.f), 1.f);
    g1 = fminf(fmaxf(g1, -1.f), 1.f);
    float mn = fminf(g0, g1);
    red[tid] = mn; __syncthreads();
    for (int s = 128; s > 0; s >>= 1) { if (tid < s) red[tid] = fminf(red[tid], red[tid + s]); __syncthreads(); }
    mn = red[0]; __syncthreads();
    float e0 = expf(mn - g0), e1 = expf(mn - g1);
    red[tid] = e0 + e1; __syncthreads();
    for (int s = 128; s > 0; s >>= 1) { if (tid < s) red[tid] += red[tid + s]; __syncthreads(); }
    float inv = 1.f / red[0];
    if (GS) {
        outb[base + tid] = f2b(b2f(gatedb[base + tid]) * (e0 * inv));
        outb[base + tid + 256] = f2b(b2f(gatedb[base + tid + 256]) * (e1 * inv));
    } else {
        outb[base + tid] = f2b(e0 * inv);
        outb[base + tid + 256] = f2b(e1 * inv);
    }
}

// token selection stage 1
__global__ __launch_bounds__(256) void ts1_k(const float* __restrict__ x, const float* __restrict__ cls_w,
                                             const float* __restrict__ cls_b, const float* __restrict__ tw,
                                             const float* __restrict__ prelu_a,
                                             float* __restrict__ combined, float* __restrict__ vals) {
    __shared__ float cw[2048];
    const int tid = threadIdx.x;
    for (int i = tid; i < 2048; i += 256) cw[i] = cls_w[i];
    __syncthreads();
    const int lane = tid & 63, wid = tid >> 6;
    const int row = blockIdx.x * 4 + wid;
    const float* xr = x + (size_t)row * 512 + lane * 8;
    float pa0 = 0, pa1 = 0, pa2 = 0, pa3 = 0;
#pragma unroll
    for (int j = 0; j < 8; j++) {
        float v = xr[j];
        int c = lane * 8 + j;
        pa0 += v * cw[c]; pa1 += v * cw[512 + c]; pa2 += v * cw[1024 + c]; pa3 += v * cw[1536 + c];
    }
#pragma unroll
    for (int o = 32; o > 0; o >>= 1) {
        pa0 += __shfl_down(pa0, o); pa1 += __shfl_down(pa1, o);
        pa2 += __shfl_down(pa2, o); pa3 += __shfl_down(pa3, o);
    }
    if (lane == 0) {
        float a = prelu_a[0];
        float sc[4] = {pa0, pa1, pa2, pa3};
        float comb = 0.f, vsum = 0.f;
#pragma unroll
        for (int s = 0; s < 4; s++) {
            float p = sc[s] + cls_b[s];
            p = (p >= 0.f) ? p : a * p;
            float cel = (p > 0.f) ? p : expm1f(p);
            float sil = p * sigm(p);
            float gel = 0.5f * p * (1.f + erff(p * 0.70710678f));
            float ts = cel * sil + gel;
            float ww = tw[s];
            float se = 1.05070099f * ((ww > 0.f) ? ww : 1.67326324f * expm1f(ww));
            comb += se * ts;
            vsum += ts;
        }
        combined[row] = comb;
        vals[row] = vsum;
    }
}

// token selection stage 2: rank via float4 LDS reads + deep unroll (ILP)
__global__ __launch_bounds__(256) void ts2_k(const float* __restrict__ combined, const float* __restrict__ vals,
                                             float* __restrict__ imp) {
    __shared__ float c[4096];
    const int b = blockIdx.y;
    const int tid = threadIdx.x;
    const float* cr = combined + b * 4096;
    for (int i = tid; i < 4096; i += 256) c[i] = cr[i];
    __syncthreads();
    const int p = blockIdx.x * 256 + tid;
    const float cp = c[p];
    const f32x4* c4 = (const f32x4*)c;
    int rank = 0;
#pragma unroll 8
    for (int q4 = 0; q4 < 1024; q4++) {
        f32x4 v = c4[q4];
        int base = q4 * 4;
        rank += (v[0] > cp) || (v[0] == cp && (base + 0) < p);
        rank += (v[1] > cp) || (v[1] == cp && (base + 1) < p);
        rank += (v[2] > cp) || (v[2] == cp && (base + 2) < p);
        rank += (v[3] > cp) || (v[3] == cp && (base + 3) < p);
    }
    imp[b * 4096 + p] = 1.f + vals[b * 4096 + rank];
}

// moe gradient base over n=65536
__global__ __launch_bounds__(256) void moe_g_k(const float* __restrict__ imp, float* __restrict__ gmoe,
                                               float* __restrict__ sspart, const float* __restrict__ scalM,
                                               const float* __restrict__ tsw, const float* __restrict__ tsa,
                                               const float* __restrict__ tsb, const float* __restrict__ tsmix) {
    __shared__ float red[256];
    const int tid = threadIdx.x;
    const float M = scalM[0];
    float w[4];
    {
        float wm = fmaxf(fmaxf(tsw[0], tsw[1]), fmaxf(tsw[2], tsw[3]));
        float s = 0.f;
#pragma unroll
        for (int k = 0; k < 4; k++) { w[k] = expf(tsw[k] - wm); s += w[k]; }
#pragma unroll
        for (int k = 0; k < 4; k++) w[k] /= s;
    }
    const float beta = tsb[0];
    float m0 = tsmix[0], m1 = tsmix[1];
    float mm = fmaxf(m0, m1);
    float e0 = expf(m0 - mm), e1 = expf(m1 - mm);
    float minv = 1.f / (e0 + e1);
    const float mix0 = e0 * minv, mix1 = e1 * minv;

    float ss = 0.f;
    int i = blockIdx.x * 256 + tid;
    const int stride = gridDim.x * 256;
    for (; i < 65536; i += stride) {
        float dv = imp[i];
        float gbv = 0.f;
#pragma unroll
        for (int s = 0; s < 4; s++) {
            float al = tsa[s];
            float H = rippleH(dv / (M * al), beta, mix0, mix1);
            gbv += w[s] * H / (M * al);
            ss += w[s] * H * dv / al;
        }
        gmoe[i] = gbv;
    }
    red[tid] = ss; __syncthreads();
    for (int s = 128; s > 0; s >>= 1) { if (tid < s) red[tid] += red[tid + s]; __syncthreads(); }
    if (tid == 0) sspart[blockIdx.x] = red[0];
}

// moe softmin per batch row (4096): sel = 1 + softmax(-clip(g - amax_corr))
__global__ __launch_bounds__(256) void moe_sel_k(const float* __restrict__ gmoe, const float* __restrict__ scalM,
                                                 const int* __restrict__ scalI, const float* __restrict__ ssTot,
                                                 float* __restrict__ sel) {
    __shared__ float red[256];
    const int tid = threadIdx.x;
    const int b = blockIdx.x;
    const float M = scalM[0];
    const int amax = scalI[0];
    const float corr = ssTot[0] / (M * M);
    float g[16];
    float mn = 3.4e38f;
#pragma unroll
    for (int k = 0; k < 16; k++) {
        int i = b * 4096 + tid + k * 256;
        float v = gmoe[i];
        if (i == amax) v -= corr;
        v = fminf(fmaxf(v, -1.f), 1.f);
        g[k] = v;
        mn = fminf(mn, v);
    }
    red[tid] = mn; __syncthreads();
    for (int s = 128; s > 0; s >>= 1) { if (tid < s) red[tid] = fminf(red[tid], red[tid + s]); __syncthreads(); }
    mn = red[0]; __syncthreads();
    float sum = 0.f;
#pragma unroll
    for (int k = 0; k < 16; k++) { g[k] = expf(mn - g[k]); sum += g[k]; }
    red[tid] = sum; __syncthreads();
    for (int s = 128; s > 0; s >>= 1) { if (tid < s) red[tid] += red[tid + s]; __syncthreads(); }
    float inv = 1.f / red[0];
#pragma unroll
    for (int k = 0; k < 16; k++) sel[b * 4096 + tid + k * 256] = 1.f + g[k] * inv;
}

// ---------------- workspace layout (bytes) ----------------
static constexpr size_t OFF_XB    = 0;                       // ushort NE (also: PV partials f32 32MB; later probs2b)
static constexpr size_t OFF_TMPB  = 16777216;                // ushort NE (later: gsb)
static constexpr size_t OFF_SPB   = 33554432;                // ushort NE
static constexpr size_t OFF_SPT   = 50331648;                // ushort NE   ([4][512][4096])
static constexpr size_t OFF_DBUF  = 67108864;                // float NE    (gxa / Sb / d1 / attn)
static constexpr size_t OFF_HBUF  = 100663296;               // float NE    (gaa / P / H)
static constexpr size_t OFF_GATB  = 134217728;               // ushort NE
static constexpr size_t OFF_NXB   = 150994944;               // ushort NE
static constexpr size_t OFF_EAB   = 167772160;               // ushort NE
static constexpr size_t OFF_AST   = 184549376;               // 512*512 ushort
static constexpr size_t OFF_WSP   = 185073664;
static constexpr size_t OFF_WSIL  = 185597952;
static constexpr size_t OFF_WOH   = 186122240;
static constexpr size_t OFF_WOUT  = 186646528;
static constexpr size_t OFF_WIGT  = 187170816;               // 4*128*128 ushort
static constexpr size_t OFF_WAGT  = 187301888;
static constexpr size_t OFF_POOL  = 187432960;               // 2048 uint
static constexpr size_t OFF_SCAL  = 187441152;               // 64 float
static constexpr size_t OFF_SCALI = 187441408;               // 64 int
static constexpr size_t OFF_BMAX  = 187441664;               // 2048 float
static constexpr size_t OFF_BIDX  = 187449856;               // 2048 int
static constexpr size_t OFF_SSP   = 187458048;               // 2048 float
static constexpr size_t OFF_COMB  = 187466240;               // 65536 float
static constexpr size_t OFF_VALS  = 187728384;
static constexpr size_t OFF_IMP   = 187990528;
static constexpr size_t OFF_GMOE  = 188252672;
static constexpr size_t OFF_SEL   = 188514816;
static constexpr size_t WS_NEED   = 188776960;

extern "C" void kernel_launch(void* const* d_in, const int* in_sizes, int n_in,
                              void* d_out, int out_size, void* d_ws, size_t ws_size,
                              hipStream_t stream)
{
    (void)in_sizes; (void)n_in; (void)out_size;
    const float* x    = (const float*)d_in[0];
    const float* AS   = (const float*)d_in[1];
    const float* Wsp  = (const float*)d_in[2];
    const float* Wsil = (const float*)d_in[3];
    const float* Woh  = (const float*)d_in[4];
    const float* Wout = (const float*)d_in[5];
    const float* wig  = (const float*)d_in[6];
    const float* wag  = (const float*)d_in[7];
    const float* a_param = (const float*)d_in[8];
    const float* cls_w = (const float*)d_in[9];
    const float* cls_b = (const float*)d_in[10];
    const float* tokw  = (const float*)d_in[11];
    const float* prelu = (const float*)d_in[12];
    const float* tsw   = (const float*)d_in[13];
    const float* tsa   = (const float*)d_in[14];
    const float* tsb   = (const float*)d_in[15];
    const float* tsmix = (const float*)d_in[16];
    const float* p1a = (const float*)d_in[17];
    const float* p1b = (const float*)d_in[18];
    const float* p1m = (const float*)d_in[19];
    const float* p2a = (const float*)d_in[20];
    const float* p2b = (const float*)d_in[21];
    const float* p2m = (const float*)d_in[22];
    float* out = (float*)d_out;

    char* w = (char*)d_ws;
    if (ws_size < WS_NEED) { sentinel_k<<<1, 256, 0, stream>>>(out); return; }

    ushort* xb    = (ushort*)(w + OFF_XB);
    ushort* tmpb  = (ushort*)(w + OFF_TMPB);
    ushort* spb   = (ushort*)(w + OFF_SPB);
    ushort* spT   = (ushort*)(w + OFF_SPT);
    float*  dbuf  = (float*)(w + OFF_DBUF);
    float*  Hbuf  = (float*)(w + OFF_HBUF);
    ushort* Sb    = (ushort*)(w + OFF_DBUF);   // alias
    ushort* Pb    = (ushort*)(w + OFF_HBUF);   // alias
    float*  gxa   = (float*)(w + OFF_DBUF);    // alias
    float*  gaa   = (float*)(w + OFF_HBUF);    // alias
    float*  pvpart= (float*)(w + OFF_XB);      // alias (32MB: XB+TMPB), used only during attention pool
    ushort* gatedb= (ushort*)(w + OFF_GATB);
    ushort* nxb   = (ushort*)(w + OFF_NXB);
    ushort* eab   = (ushort*)(w + OFF_EAB);
    ushort* ASt   = (ushort*)(w + OFF_AST);
    ushort* Wspb  = (ushort*)(w + OFF_WSP);
    ushort* Wsilb = (ushort*)(w + OFF_WSIL);
    ushort* Wohb  = (ushort*)(w + OFF_WOH);
    ushort* Woutb = (ushort*)(w + OFF_WOUT);
    ushort* wigT  = (ushort*)(w + OFF_WIGT);
    ushort* wagT  = (ushort*)(w + OFF_WAGT);
    uint*   poolU = (uint*)(w + OFF_POOL);
    float*  scal  = (float*)(w + OFF_SCAL);
    int*    scalI = (int*)(w + OFF_SCALI);
    float*  bmax  = (float*)(w + OFF_BMAX);
    int*    bidx  = (int*)(w + OFF_BIDX);
    float*  sspart= (float*)(w + OFF_SSP);
    float*  comb  = (float*)(w + OFF_COMB);
    float*  vals  = (float*)(w + OFF_VALS);
    float*  imp   = (float*)(w + OFF_IMP);
    float*  gmoe  = (float*)(w + OFF_GMOE);
    float*  sel   = (float*)(w + OFF_SEL);
    ushort* gsb     = tmpb;   // reuse (after attention pool)
    ushort* probs2b = xb;     // reuse (after attention pool)

    // ---- prep ----
    convert_f2b_k<<<2048, 256, 0, stream>>>(x, xb, NE >> 2);
    convert_f2b_k<<<64, 256, 0, stream>>>(Wsp, Wspb, 65536);
    convert_f2b_k<<<64, 256, 0, stream>>>(Wsil, Wsilb, 65536);
    convert_f2b_k<<<64, 256, 0, stream>>>(Woh, Wohb, 65536);
    convert_f2b_k<<<64, 256, 0, stream>>>(Wout, Woutb, 65536);
    transpose_to_bf16<true><<<dim3(16, 16, 1), 256, 0, stream>>>(AS, ASt, 512, 512);
    transpose_to_bf16<true><<<dim3(4, 4, 4), 256, 0, stream>>>(wig, wigT, 128, 128);
    transpose_to_bf16<true><<<dim3(4, 4, 4), 256, 0, stream>>>(wag, wagT, 128, 128);
    init_pool_k<<<8, 256, 0, stream>>>(poolU);

    // ---- G1: tmp = x @ AS ; G2: spatial = tmp @ Wsp^T ----
    gemm_bt<1><<<dim3(4, 128), 256, 0, stream>>>(xb, 512, ASt, 512, tmpb, 512, 512, nullptr);
    gemm_bt<1><<<dim3(4, 128), 256, 0, stream>>>(tmpb, 512, Wspb, 512, spb, 512, 512, nullptr);

    // ---- gates: batched block-diag GEMMs then elementwise ----
    gate_gemm_k<<<dim3(2, 128, 4), 256, 0, stream>>>(xb, wigT, wagT, gxa, gaa);
    gates_elem_k<<<2048, 256, 0, stream>>>(x, gxa, gaa, a_param, nxb, eab);

    // ---- attention pool (per batch) ----
    transpose_to_bf16<false><<<dim3(16, 128, 4), 256, 0, stream>>>(spb, spT, 4096, 512);
    const float sc128 = 0.0883883476f;
    for (int b = 0; b < 4; b++) {
        const ushort* spB = spb + (size_t)b * L_ * D_;
        gemm_bt<1><<<dim3(32, 32), 256, 0, stream>>>(spB, 512, spB, 512, Sb, 4096, 512, nullptr);
        softmax_rows_k<<<4096, 256, 0, stream>>>(Sb, Pb, sc128);
        pv_split_k<<<dim3(4, 32, 4), 256, 0, stream>>>(Pb, spT + (size_t)b * D_ * L_, pvpart);
        pool_combine_k<<<128, 256, 0, stream>>>(pvpart, poolU + b * 512);
    }

    // ---- gated = exp(log_a)*pool + nx ----
    gated_k<<<1024, 256, 0, stream>>>(eab, nxb, poolU, gatedb);

    // ---- sparsity = ripple_act(gated @ Wsil^T) ; gs = gated * sparsity ----
    gemm_bt<0><<<dim3(4, 128), 256, 0, stream>>>(gatedb, 512, Wsilb, 512, dbuf, 512, 512, nullptr);
    redmax1_k<<<1024, 256, 0, stream>>>(dbuf, NE, bmax, bidx);
    redmax2_k<<<1, 256, 0, stream>>>(bmax, bidx, 1024, &scal[0], &scalI[0]);
    ripple_g_k<<<2048, 256, 0, stream>>>(dbuf, Hbuf, sspart, &scal[0], p1a, p1b, p1m);
    redsum2_k<<<1, 256, 0, stream>>>(sspart, 2048, &scal[1]);
    ripple_softmax_k<1><<<16384, 256, 0, stream>>>(Hbuf, &scal[0], &scalI[0], &scal[1], p1a, gatedb, gsb);

    // ---- token selection -> sel ----
    ts1_k<<<4096, 256, 0, stream>>>(x, cls_w, cls_b, tokw, prelu, comb, vals);
    ts2_k<<<dim3(16, 4), 256, 0, stream>>>(comb, vals, imp);
    redmax1_k<<<64, 256, 0, stream>>>(imp, 65536, bmax, bidx);
    redmax2_k<<<1, 256, 0, stream>>>(bmax, bidx, 64, &scal[4], &scalI[2]);
    moe_g_k<<<64, 256, 0, stream>>>(imp, gmoe, sspart, &scal[4], tsw, tsa, tsb, tsmix);
    redsum2_k<<<1, 256, 0, stream>>>(sspart, 64, &scal[5]);
    moe_sel_k<<<4, 256, 0, stream>>>(gmoe, &scal[4], &scalI[2], &scal[5], sel);

    // ---- attn = gs @ Woh^T, scaled by sel ----
    gemm_bt<3><<<dim3(4, 128), 256, 0, stream>>>(gsb, 512, Wohb, 512, dbuf, 512, 512, sel);

    // ---- out_probs = ripple_act(d2) ----
    redmax1_k<<<1024, 256, 0, stream>>>(dbuf, NE, bmax, bidx);
    redmax2_k<<<1, 256, 0, stream>>>(bmax, bidx, 1024, &scal[2], &scalI[1]);
    ripple_g_k<<<2048, 256, 0, stream>>>(dbuf, Hbuf, sspart, &scal[2], p2a, p2b, p2m);
    redsum2_k<<<1, 256, 0, stream>>>(sspart, 2048, &scal[3]);
    ripple_softmax_k<0><<<16384, 256, 0, stream>>>(Hbuf, &scal[2], &scalI[1], &scal[3], p2a, nullptr, probs2b);

    // ---- out = probs @ Wout^T ----
    gemm_bt<0><<<dim3(4, 128), 256, 0, stream>>>(probs2b, 512, Woutb, 512, out, 512, 512, nullptr);
}

// Round 4
// 726.191 us; speedup vs baseline: 5.7135x; 1.1794x over previous
//
#include <hip/hip_runtime.h>

typedef unsigned short ushort;
typedef unsigned int uint;

#define DEV __device__ __forceinline__

typedef __attribute__((ext_vector_type(4))) float f32x4;
typedef __bf16 bf16x8 __attribute__((ext_vector_type(8)));
typedef __attribute__((ext_vector_type(4))) ushort u16x4;
typedef __attribute__((ext_vector_type(8))) ushort u16x8;

static constexpr int B_ = 4, L_ = 4096, D_ = 512;
static constexpr long NE = (long)B_ * L_ * D_;      // 8388608
static constexpr int ROWS = B_ * L_;                // 16384

// ---------------- small helpers ----------------
DEV float b2f(ushort u) { return __uint_as_float(((uint)u) << 16); }
DEV ushort f2b(float f) {
    uint u = __float_as_uint(f);
    uint r = u + 0x7FFFu + ((u >> 16) & 1u);
    return (ushort)(r >> 16);
}
DEV uint mapF(float f) {
    uint b = __float_as_uint(f);
    return (b & 0x80000000u) ? ~b : (b | 0x80000000u);
}
DEV float unmapF(uint u) {
    uint b = (u & 0x80000000u) ? (u & 0x7FFFFFFFu) : ~u;
    return __uint_as_float(b);
}
DEV float sigm(float x) { return 1.f / (1.f + expf(-x)); }

// async global->LDS, 16B per lane, wave-uniform LDS base
DEV void gload16(const ushort* g, ushort* l) {
    __builtin_amdgcn_global_load_lds((const __attribute__((address_space(1))) void*)g,
                                     (__attribute__((address_space(3))) void*)l, 16, 0, 0);
}

// trigamma(t+1), t in (-1,1)
DEV float trigamma1p(float t) {
    float x = t + 1.f;
    float acc = 0.f;
#pragma unroll
    for (int k = 0; k < 6; k++) { float xx = x + (float)k; acc += 1.f / (xx * xx); }
    float y = x + 6.f;
    float iy = 1.f / y, iy2 = iy * iy;
    return acc + iy * (1.f + iy * (0.5f + iy * (0.166666667f + iy2 * (-0.0333333333f + iy2 * 0.0238095238f))));
}
// I1(t), |t|<~1.2: power series
DEV float besselI1(float t) {
    float q = 0.25f * t * t;
    return 0.5f * t * (1.f + q * (0.5f + q * (0.0833333333f + q * (0.00694444444f + q * (3.47222222e-4f + q * 1.15740741e-5f)))));
}
DEV float rippleH(float u, float beta, float mix0, float mix1) {
    float t = beta * erff(u);
    float Tp = mix0 * trigamma1p(t) + mix1 * besselI1(t);
    float ep = 1.12837917f * expf(-u * u);
    return beta * Tp * ep;
}

// ---------------- shared GEMM core: 128x128 tile, K-loop, bf16 MFMA ----------------
// A pre-offset to tile row 0 (lda elems/row); Bt pre-offset to tile col 0 (ldb elems/row).
// Staging: global_load_lds width=16. Wave w stages rows [w*16, w*16+16) of each half-tile;
// lane l -> row w*16 + (l>>2), 16B quarter (l&3). LDS layout: [128][32] ushort row-major.
DEV void gemm_core(const ushort* __restrict__ A, int lda,
                   const ushort* __restrict__ Bt, int ldb, int K,
                   ushort* __restrict__ Alds, ushort* __restrict__ Blds,
                   f32x4 (&acc)[4][4])
{
    const int tid = threadIdx.x;
    const int lane = tid & 63;
    const int wave = tid >> 6;
    const int wr = wave >> 1, wc = wave & 1;

    const int srow = wave * 16 + (lane >> 2);
    const int skc = (lane & 3) * 8;
    const ushort* Ag0 = A + (size_t)srow * lda + skc;
    const ushort* Ag1 = A + (size_t)(srow + 64) * lda + skc;
    const ushort* Bg0 = Bt + (size_t)srow * ldb + skc;
    const ushort* Bg1 = Bt + (size_t)(srow + 64) * ldb + skc;
    ushort* Al0 = Alds + wave * 512;          // wave-uniform LDS bases
    ushort* Al1 = Alds + 2048 + wave * 512;
    ushort* Bl0 = Blds + wave * 512;
    ushort* Bl1 = Blds + 2048 + wave * 512;

    const int ar = wr * 64 + (lane & 15);
    const int br = wc * 64 + (lane & 15);
    const int kk = (lane >> 4) * 8;

    for (int k0 = 0; k0 < K; k0 += 32) {
        __syncthreads();
        gload16(Ag0 + k0, Al0);
        gload16(Ag1 + k0, Al1);
        gload16(Bg0 + k0, Bl0);
        gload16(Bg1 + k0, Bl1);
        __syncthreads();   // compiler emits s_waitcnt vmcnt(0) before s_barrier
        bf16x8 af[4], bfr[4];
#pragma unroll
        for (int mi = 0; mi < 4; mi++) af[mi] = *(const bf16x8*)&Alds[(ar + mi * 16) * 32 + kk];
#pragma unroll
        for (int ni = 0; ni < 4; ni++) bfr[ni] = *(const bf16x8*)&Blds[(br + ni * 16) * 32 + kk];
#pragma unroll
        for (int mi = 0; mi < 4; mi++)
#pragma unroll
            for (int ni = 0; ni < 4; ni++)
                acc[mi][ni] = __builtin_amdgcn_mfma_f32_16x16x32_bf16(af[mi], bfr[ni], acc[mi][ni], 0, 0, 0);
    }
}

// ---------------- GEMM: C[M,N] = A[M,K] * Bt[N,K]^T ----------------
// MODE 0: f32 out; 1: bf16 out; 3: f32 out scaled by rowScale[global row]
template <int MODE>
__global__ __launch_bounds__(256, 2) void gemm_bt(
    const ushort* __restrict__ A, int lda,
    const ushort* __restrict__ Bt, int ldb,
    void* __restrict__ Cv, int ldc, int K,
    const float* __restrict__ rowScale)
{
    __shared__ ushort Alds[128 * 32];
    __shared__ ushort Blds[128 * 32];
    const int row0 = blockIdx.y * 128, col0 = blockIdx.x * 128;
    f32x4 acc[4][4] = {};
    gemm_core(A + (size_t)row0 * lda, lda, Bt + (size_t)col0 * ldb, ldb, K, Alds, Blds, acc);

    const int tid = threadIdx.x;
    const int lane = tid & 63;
    const int wave = tid >> 6;
    const int wr = wave >> 1, wc = wave & 1;
    const int ocol = col0 + wc * 64 + (lane & 15);
#pragma unroll
    for (int mi = 0; mi < 4; mi++) {
        const int rbase = row0 + wr * 64 + mi * 16 + (lane >> 4) * 4;
#pragma unroll
        for (int j = 0; j < 4; j++) {
            float sc = (MODE == 3) ? rowScale[rbase + j] : 1.f;
#pragma unroll
            for (int ni = 0; ni < 4; ni++) {
                float v = acc[mi][ni][j] * sc;
                int cc = ocol + ni * 16;
                if (MODE == 1) ((ushort*)Cv)[(size_t)(rbase + j) * ldc + cc] = f2b(v);
                else ((float*)Cv)[(size_t)(rbase + j) * ldc + cc] = v;
            }
        }
    }
}

// ---------------- PV split-K: part[ks][4096][512] = P[:, ks*1024:(ks+1)*1024] @ V ----------------
__global__ __launch_bounds__(256, 2) void pv_split_k(const ushort* __restrict__ P, const ushort* __restrict__ Vt,
                                                     float* __restrict__ part)
{
    __shared__ ushort Alds[128 * 32];
    __shared__ ushort Blds[128 * 32];
    const int ks = blockIdx.z;
    const int row0 = blockIdx.y * 128, col0 = blockIdx.x * 128;
    f32x4 acc[4][4] = {};
    gemm_core(P + (size_t)row0 * 4096 + ks * 1024, 4096,
              Vt + (size_t)col0 * 4096 + ks * 1024, 4096, 1024, Alds, Blds, acc);

    float* C = part + (size_t)ks * 2097152 + (size_t)row0 * 512 + col0;
    const int tid = threadIdx.x;
    const int lane = tid & 63;
    const int wave = tid >> 6;
    const int wr = wave >> 1, wc = wave & 1;
    const int ocol = wc * 64 + (lane & 15);
#pragma unroll
    for (int mi = 0; mi < 4; mi++) {
        const int rl = wr * 64 + mi * 16 + (lane >> 4) * 4;
#pragma unroll
        for (int j = 0; j < 4; j++)
#pragma unroll
            for (int ni = 0; ni < 4; ni++)
                C[(size_t)(rl + j) * 512 + ocol + ni * 16] = acc[mi][ni][j];
    }
}

// combine: pool[d] = max over l of sum_ks part[ks][l][d]; 128 blocks x 32 rows
__global__ __launch_bounds__(256) void pool_combine_k(const float* __restrict__ part, uint* __restrict__ poolU)
{
    const int tid = threadIdx.x;
    const int l0 = blockIdx.x * 32;
    float m0 = -3.4e38f, m1 = -3.4e38f;
    for (int l = 0; l < 32; l++) {
        size_t off = (size_t)(l0 + l) * 512;
        float s0 = 0.f, s1 = 0.f;
#pragma unroll
        for (int ks = 0; ks < 4; ks++) {
            s0 += part[(size_t)ks * 2097152 + off + tid];
            s1 += part[(size_t)ks * 2097152 + off + tid + 256];
        }
        m0 = fmaxf(m0, s0); m1 = fmaxf(m1, s1);
    }
    atomicMax(&poolU[tid], mapF(m0));
    atomicMax(&poolU[tid + 256], mapF(m1));
}

// ---------------- batched block-diag gate GEMMs: grid (2, 128, 4) ----------------
__global__ __launch_bounds__(256, 2) void gate_gemm_k(const ushort* __restrict__ xb,
                                                      const ushort* __restrict__ wigT, const ushort* __restrict__ wagT,
                                                      float* __restrict__ gxa, float* __restrict__ gaa)
{
    __shared__ ushort Alds[128 * 32];
    __shared__ ushort Blds[128 * 32];
    const int which = blockIdx.x;
    const int h = blockIdx.z;
    const ushort* A = xb + (size_t)blockIdx.y * 128 * 512 + h * 128;
    const ushort* W = (which ? wagT : wigT) + (size_t)h * 16384;
    f32x4 acc[4][4] = {};
    gemm_core(A, 512, W, 128, 128, Alds, Blds, acc);

    float* C = (which ? gaa : gxa) + (size_t)blockIdx.y * 128 * 512 + h * 128;
    const int tid = threadIdx.x;
    const int lane = tid & 63;
    const int wave = tid >> 6;
    const int wr = wave >> 1, wc = wave & 1;
    const int ocol = wc * 64 + (lane & 15);
#pragma unroll
    for (int mi = 0; mi < 4; mi++) {
        const int rl = wr * 64 + mi * 16 + (lane >> 4) * 4;
#pragma unroll
        for (int j = 0; j < 4; j++)
#pragma unroll
            for (int ni = 0; ni < 4; ni++)
                C[(size_t)(rl + j) * 512 + ocol + ni * 16] = acc[mi][ni][j];
    }
}

// ---------------- misc kernels ----------------
__global__ void convert_f2b_k(const float* __restrict__ s, ushort* __restrict__ d, long n4) {
    long i = (long)blockIdx.x * blockDim.x + threadIdx.x;
    long st = (long)gridDim.x * blockDim.x;
    for (; i < n4; i += st) {
        f32x4 v = ((const f32x4*)s)[i];
        u16x4 o;
        o[0] = f2b(v[0]); o[1] = f2b(v[1]); o[2] = f2b(v[2]); o[3] = f2b(v[3]);
        ((u16x4*)d)[i] = o;
    }
}

template <bool SRCF32>
__global__ __launch_bounds__(256) void transpose_to_bf16(const void* __restrict__ srcv, ushort* __restrict__ dst, int R, int C) {
    __shared__ float tile[32][33];
    const int z = blockIdx.z;
    const float* sf = (const float*)srcv + (size_t)z * R * C;
    const ushort* sb = (const ushort*)srcv + (size_t)z * R * C;
    ushort* dz = dst + (size_t)z * R * C;
    const int tx = threadIdx.x & 31, ty = threadIdx.x >> 5;
    const int c = blockIdx.x * 32 + tx;
#pragma unroll
    for (int k = 0; k < 4; k++) {
        const int r = blockIdx.y * 32 + ty + k * 8;
        tile[ty + k * 8][tx] = SRCF32 ? sf[(size_t)r * C + c] : b2f(sb[(size_t)r * C + c]);
    }
    __syncthreads();
#pragma unroll
    for (int k = 0; k < 4; k++) {
        const int dr = blockIdx.x * 32 + ty + k * 8;
        const int dc = blockIdx.y * 32 + tx;
        dz[(size_t)dr * R + dc] = f2b(tile[tx][ty + k * 8]);
    }
}

__global__ void init_pool_k(uint* poolU) {
    int i = blockIdx.x * 256 + threadIdx.x;
    if (i < 2048) poolU[i] = 0u;
}
__global__ void sentinel_k(float* o) { o[threadIdx.x] = 1.0e6f; }

// gates elementwise (x4 vectorized)
__global__ __launch_bounds__(256) void gates_elem_k(const float* __restrict__ x, const float* __restrict__ gxa,
                                                    const float* __restrict__ gaa, const float* __restrict__ a_param,
                                                    ushort* __restrict__ nxb, ushort* __restrict__ eab) {
    __shared__ float sp8[512];
    const int tid = threadIdx.x;
    for (int d = tid; d < 512; d += 256) {
        float a = a_param[d];
        sp8[d] = 8.f * (fmaxf(a, 0.f) + log1pf(expf(-fabsf(a))));
    }
    __syncthreads();
    long i = (long)blockIdx.x * blockDim.x + tid;
    long st = (long)gridDim.x * blockDim.x;
    const long n4 = NE >> 2;
    for (; i < n4; i += st) {
        f32x4 xv = ((const f32x4*)x)[i];
        f32x4 gx4 = ((const f32x4*)gxa)[i];
        f32x4 ga4 = ((const f32x4*)gaa)[i];
        u16x4 nx4, ea4;
        long e = i << 2;
#pragma unroll
        for (int j = 0; j < 4; j++) {
            int d = (int)((e + j) & 511);
            float la = -sp8[d] * sigm(ga4[j]);
            float ea = expf(la);
            float nx = xv[j] * sigm(gx4[j]) * sqrtf(fmaxf(1.f - expf(2.f * la), 0.f));
            nx4[j] = f2b(nx);
            ea4[j] = f2b(ea);
        }
        ((u16x4*)nxb)[i] = nx4;
        ((u16x4*)eab)[i] = ea4;
    }
}

// row softmax over N=4096 bf16 -> bf16
__global__ __launch_bounds__(256) void softmax_rows_k(const ushort* __restrict__ S, ushort* __restrict__ P, float scale) {
    __shared__ float red[256];
    const int tid = threadIdx.x;
    const ushort* row = S + (size_t)blockIdx.x * 4096;
    float vals[16];
    bf16x8 v0 = *(const bf16x8*)&row[tid * 16];
    bf16x8 v1 = *(const bf16x8*)&row[tid * 16 + 8];
    float mx = -3.4e38f;
#pragma unroll
    for (int k = 0; k < 8; k++) { vals[k] = (float)v0[k] * scale; mx = fmaxf(mx, vals[k]); }
#pragma unroll
    for (int k = 0; k < 8; k++) { vals[8 + k] = (float)v1[k] * scale; mx = fmaxf(mx, vals[8 + k]); }
    red[tid] = mx; __syncthreads();
    for (int s = 128; s > 0; s >>= 1) { if (tid < s) red[tid] = fmaxf(red[tid], red[tid + s]); __syncthreads(); }
    mx = red[0]; __syncthreads();
    float sum = 0.f;
#pragma unroll
    for (int k = 0; k < 16; k++) { vals[k] = expf(vals[k] - mx); sum += vals[k]; }
    red[tid] = sum; __syncthreads();
    for (int s = 128; s > 0; s >>= 1) { if (tid < s) red[tid] += red[tid + s]; __syncthreads(); }
    float inv = 1.f / red[0];
    ushort* prow = P + (size_t)blockIdx.x * 4096;
#pragma unroll
    for (int k = 0; k < 16; k++) prow[tid * 16 + k] = f2b(vals[k] * inv);
}

// gated = ea*pool[b,d] + nx  (x8 vectorized)
__global__ __launch_bounds__(256) void gated_k(const ushort* __restrict__ eab, const ushort* __restrict__ nxb,
                                               const uint* __restrict__ poolU, ushort* __restrict__ gatedb) {
    long i = (long)blockIdx.x * blockDim.x + threadIdx.x;
    long st = (long)gridDim.x * blockDim.x;
    const long n8 = NE >> 3;
    for (; i < n8; i += st) {
        u16x8 ea8 = ((const u16x8*)eab)[i];
        u16x8 nx8 = ((const u16x8*)nxb)[i];
        u16x8 o;
        long e = i << 3;
        int b = (int)(e >> 21);
        int d0 = (int)(e & 511);
#pragma unroll
        for (int j = 0; j < 8; j++) {
            float pl = unmapF(poolU[b * 512 + d0 + j]);
            o[j] = f2b(b2f(ea8[j]) * pl + b2f(nx8[j]));
        }
        ((u16x8*)gatedb)[i] = o;
    }
}

// global max + argmax (stage1), n elements
__global__ __launch_bounds__(256) void redmax1_k(const float* __restrict__ d, long n, float* __restrict__ bmax, int* __restrict__ bidx) {
    __shared__ float rv[256];
    __shared__ int ri[256];
    const int tid = threadIdx.x;
    long g = (long)blockIdx.x * 256 + tid;
    const long stride = (long)gridDim.x * 256;
    float bv = -3.4e38f; int bi = -1;
    for (long i = g; i < n; i += stride) {
        float v = d[i];
        if (v > bv) { bv = v; bi = (int)i; }
    }
    rv[tid] = bv; ri[tid] = bi; __syncthreads();
    for (int s = 128; s > 0; s >>= 1) {
        if (tid < s) {
            float ov = rv[tid + s]; int oi = ri[tid + s];
            if (oi >= 0 && (ri[tid] < 0 || ov > rv[tid] || (ov == rv[tid] && oi < ri[tid]))) { rv[tid] = ov; ri[tid] = oi; }
        }
        __syncthreads();
    }
    if (tid == 0) { bmax[blockIdx.x] = rv[0]; bidx[blockIdx.x] = ri[0]; }
}
__global__ __launch_bounds__(256) void redmax2_k(const float* __restrict__ bmax, const int* __restrict__ bidx, int n,
                                                 float* __restrict__ outM, int* __restrict__ outI) {
    __shared__ float rv[256];
    __shared__ int ri[256];
    const int tid = threadIdx.x;
    float bv = -3.4e38f; int bi = -1;
    for (int i = tid; i < n; i += 256) {
        float v = bmax[i]; int ix = bidx[i];
        if (ix >= 0 && (bi < 0 || v > bv || (v == bv && ix < bi))) { bv = v; bi = ix; }
    }
    rv[tid] = bv; ri[tid] = bi; __syncthreads();
    for (int s = 128; s > 0; s >>= 1) {
        if (tid < s) {
            float ov = rv[tid + s]; int oi = ri[tid + s];
            if (oi >= 0 && (ri[tid] < 0 || ov > rv[tid] || (ov == rv[tid] && oi < ri[tid]))) { rv[tid] = ov; ri[tid] = oi; }
        }
        __syncthreads();
    }
    if (tid == 0) { outM[0] = rv[0]; outI[0] = ri[0]; }
}

// ripple gradient base
__global__ __launch_bounds__(256) void ripple_g_k(const float* __restrict__ d, float* __restrict__ gb, float* __restrict__ sspart,
                                                  const float* __restrict__ scalM, const float* __restrict__ alpha_p,
                                                  const float* __restrict__ beta_p, const float* __restrict__ mix_p) {
    __shared__ float red[256];
    const int tid = threadIdx.x;
    const float M = scalM[0];
    const float alpha = alpha_p[0], beta = beta_p[0];
    float m0 = mix_p[0], m1 = mix_p[1];
    float mm = fmaxf(m0, m1);
    float e0 = expf(m0 - mm), e1 = expf(m1 - mm);
    float inv = 1.f / (e0 + e1);
    float mix0 = e0 * inv, mix1 = e1 * inv;
    const float invMA = 1.f / (M * alpha);
    float ss = 0.f;
    long g = (long)blockIdx.x * 256 + tid;
    const long stride = (long)gridDim.x * 256;
    for (long i = g; i < NE; i += stride) {
        float dv = d[i];
        float H = rippleH(dv * invMA, beta, mix0, mix1);
        gb[i] = H * invMA;
        ss += H * dv;
    }
    red[tid] = ss; __syncthreads();
    for (int s = 128; s > 0; s >>= 1) { if (tid < s) red[tid] += red[tid + s]; __syncthreads(); }
    if (tid == 0) sspart[blockIdx.x] = red[0];
}
__global__ __launch_bounds__(256) void redsum2_k(const float* __restrict__ part, int n, float* __restrict__ out) {
    __shared__ float red[256];
    const int tid = threadIdx.x;
    float s = 0.f;
    for (int i = tid; i < n; i += 256) s += part[i];
    red[tid] = s; __syncthreads();
    for (int q = 128; q > 0; q >>= 1) { if (tid < q) red[tid] += red[tid + q]; __syncthreads(); }
    if (tid == 0) out[0] = red[0];
}

// per-row (512) softmin
template <int GS>
__global__ __launch_bounds__(256) void ripple_softmax_k(const float* __restrict__ gb,
                                                        const float* __restrict__ scalM, const int* __restrict__ scalI,
                                                        const float* __restrict__ ssTot, const float* __restrict__ alpha_p,
                                                        const ushort* __restrict__ gatedb, ushort* __restrict__ outb) {
    __shared__ float red[256];
    const int tid = threadIdx.x;
    const float M = scalM[0];
    const int amax = scalI[0];
    const float corr = ssTot[0] / (M * M * alpha_p[0]);
    long base = (long)blockIdx.x * 512;
    float g0 = gb[base + tid];
    float g1 = gb[base + tid + 256];
    if ((int)(base + tid) == amax) g0 -= corr;
    if ((int)(base + tid + 256) == amax) g1 -= corr;
    g0 = fminf(fmaxf(g0, -1.f), 1.f);
    g1 = fminf(fmaxf(g1, -1.f), 1.f);
    float mn = fminf(g0, g1);
    red[tid] = mn; __syncthreads();
    for (int s = 128; s > 0; s >>= 1) { if (tid < s) red[tid] = fminf(red[tid], red[tid + s]); __syncthreads(); }
    mn = red[0]; __syncthreads();
    float e0 = expf(mn - g0), e1 = expf(mn - g1);
    red[tid] = e0 + e1; __syncthreads();
    for (int s = 128; s > 0; s >>= 1) { if (tid < s) red[tid] += red[tid + s]; __syncthreads(); }
    float inv = 1.f / red[0];
    if (GS) {
        outb[base + tid] = f2b(b2f(gatedb[base + tid]) * (e0 * inv));
        outb[base + tid + 256] = f2b(b2f(gatedb[base + tid + 256]) * (e1 * inv));
    } else {
        outb[base + tid] = f2b(e0 * inv);
        outb[base + tid + 256] = f2b(e1 * inv);
    }
}

// token selection stage 1
__global__ __launch_bounds__(256) void ts1_k(const float* __restrict__ x, const float* __restrict__ cls_w,
                                             const float* __restrict__ cls_b, const float* __restrict__ tw,
                                             const float* __restrict__ prelu_a,
                                             float* __restrict__ combined, float* __restrict__ vals) {
    __shared__ float cw[2048];
    const int tid = threadIdx.x;
    for (int i = tid; i < 2048; i += 256) cw[i] = cls_w[i];
    __syncthreads();
    const int lane = tid & 63, wid = tid >> 6;
    const int row = blockIdx.x * 4 + wid;
    const float* xr = x + (size_t)row * 512 + lane * 8;
    float pa0 = 0, pa1 = 0, pa2 = 0, pa3 = 0;
#pragma unroll
    for (int j = 0; j < 8; j++) {
        float v = xr[j];
        int c = lane * 8 + j;
        pa0 += v * cw[c]; pa1 += v * cw[512 + c]; pa2 += v * cw[1024 + c]; pa3 += v * cw[1536 + c];
    }
#pragma unroll
    for (int o = 32; o > 0; o >>= 1) {
        pa0 += __shfl_down(pa0, o); pa1 += __shfl_down(pa1, o);
        pa2 += __shfl_down(pa2, o); pa3 += __shfl_down(pa3, o);
    }
    if (lane == 0) {
        float a = prelu_a[0];
        float sc[4] = {pa0, pa1, pa2, pa3};
        float comb = 0.f, vsum = 0.f;
#pragma unroll
        for (int s = 0; s < 4; s++) {
            float p = sc[s] + cls_b[s];
            p = (p >= 0.f) ? p : a * p;
            float cel = (p > 0.f) ? p : expm1f(p);
            float sil = p * sigm(p);
            float gel = 0.5f * p * (1.f + erff(p * 0.70710678f));
            float ts = cel * sil + gel;
            float ww = tw[s];
            float se = 1.05070099f * ((ww > 0.f) ? ww : 1.67326324f * expm1f(ww));
            comb += se * ts;
            vsum += ts;
        }
        combined[row] = comb;
        vals[row] = vsum;
    }
}

// ts2a: partial ranks. grid (16 p-chunks, 8 q-chunks, 4 batches)
__global__ __launch_bounds__(256) void ts2a_k(const float* __restrict__ combined, int* __restrict__ rankp) {
    __shared__ float q[512];
    const int b = blockIdx.z;
    const int tid = threadIdx.x;
    const float* cr = combined + b * 4096;
    const int q0 = blockIdx.y * 512;
    for (int i = tid; i < 512; i += 256) q[i] = cr[q0 + i];
    __syncthreads();
    const int p = blockIdx.x * 256 + tid;
    const float cp = cr[p];
    const f32x4* q4 = (const f32x4*)q;
    int rank = 0;
#pragma unroll 8
    for (int i4 = 0; i4 < 128; i4++) {
        f32x4 v = q4[i4];
        int qb = q0 + i4 * 4;
        rank += (v[0] > cp) || (v[0] == cp && (qb + 0) < p);
        rank += (v[1] > cp) || (v[1] == cp && (qb + 1) < p);
        rank += (v[2] > cp) || (v[2] == cp && (qb + 2) < p);
        rank += (v[3] > cp) || (v[3] == cp && (qb + 3) < p);
    }
    rankp[((b * 8 + blockIdx.y) * 4096) + p] = rank;
}

// ts2b: gather. grid (16, 4)
__global__ __launch_bounds__(256) void ts2b_k(const int* __restrict__ rankp, const float* __restrict__ vals,
                                              float* __restrict__ imp) {
    const int b = blockIdx.y;
    const int p = blockIdx.x * 256 + threadIdx.x;
    int rank = 0;
#pragma unroll
    for (int c = 0; c < 8; c++) rank += rankp[((b * 8 + c) * 4096) + p];
    imp[b * 4096 + p] = 1.f + vals[b * 4096 + rank];
}

// moe gradient base over n=65536
__global__ __launch_bounds__(256) void moe_g_k(const float* __restrict__ imp, float* __restrict__ gmoe,
                                               float* __restrict__ sspart, const float* __restrict__ scalM,
                                               const float* __restrict__ tsw, const float* __restrict__ tsa,
                                               const float* __restrict__ tsb, const float* __restrict__ tsmix) {
    __shared__ float red[256];
    const int tid = threadIdx.x;
    const float M = scalM[0];
    float w[4];
    {
        float wm = fmaxf(fmaxf(tsw[0], tsw[1]), fmaxf(tsw[2], tsw[3]));
        float s = 0.f;
#pragma unroll
        for (int k = 0; k < 4; k++) { w[k] = expf(tsw[k] - wm); s += w[k]; }
#pragma unroll
        for (int k = 0; k < 4; k++) w[k] /= s;
    }
    const float beta = tsb[0];
    float m0 = tsmix[0], m1 = tsmix[1];
    float mm = fmaxf(m0, m1);
    float e0 = expf(m0 - mm), e1 = expf(m1 - mm);
    float minv = 1.f / (e0 + e1);
    const float mix0 = e0 * minv, mix1 = e1 * minv;

    float ss = 0.f;
    int i = blockIdx.x * 256 + tid;
    const int stride = gridDim.x * 256;
    for (; i < 65536; i += stride) {
        float dv = imp[i];
        float gbv = 0.f;
#pragma unroll
        for (int s = 0; s < 4; s++) {
            float al = tsa[s];
            float H = rippleH(dv / (M * al), beta, mix0, mix1);
            gbv += w[s] * H / (M * al);
            ss += w[s] * H * dv / al;
        }
        gmoe[i] = gbv;
    }
    red[tid] = ss; __syncthreads();
    for (int s = 128; s > 0; s >>= 1) { if (tid < s) red[tid] += red[tid + s]; __syncthreads(); }
    if (tid == 0) sspart[blockIdx.x] = red[0];
}

// moe softmin per batch row (4096): sel = 1 + softmax(-clip(g - amax_corr))
__global__ __launch_bounds__(256) void moe_sel_k(const float* __restrict__ gmoe, const float* __restrict__ scalM,
                                                 const int* __restrict__ scalI, const float* __restrict__ ssTot,
                                                 float* __restrict__ sel) {
    __shared__ float red[256];
    const int tid = threadIdx.x;
    const int b = blockIdx.x;
    const float M = scalM[0];
    const int amax = scalI[0];
    const float corr = ssTot[0] / (M * M);
    float g[16];
    float mn = 3.4e38f;
#pragma unroll
    for (int k = 0; k < 16; k++) {
        int i = b * 4096 + tid + k * 256;
        float v = gmoe[i];
        if (i == amax) v -= corr;
        v = fminf(fmaxf(v, -1.f), 1.f);
        g[k] = v;
        mn = fminf(mn, v);
    }
    red[tid] = mn; __syncthreads();
    for (int s = 128; s > 0; s >>= 1) { if (tid < s) red[tid] = fminf(red[tid], red[tid + s]); __syncthreads(); }
    mn = red[0]; __syncthreads();
    float sum = 0.f;
#pragma unroll
    for (int k = 0; k < 16; k++) { g[k] = expf(mn - g[k]); sum += g[k]; }
    red[tid] = sum; __syncthreads();
    for (int s = 128; s > 0; s >>= 1) { if (tid < s) red[tid] += red[tid + s]; __syncthreads(); }
    float inv = 1.f / red[0];
#pragma unroll
    for (int k = 0; k < 16; k++) sel[b * 4096 + tid + k * 256] = 1.f + g[k] * inv;
}

// ---------------- workspace layout (bytes) ----------------
static constexpr size_t OFF_XB    = 0;                       // ushort NE (also: PV partials f32 32MB; later probs2b)
static constexpr size_t OFF_TMPB  = 16777216;                // ushort NE (later: gsb)
static constexpr size_t OFF_SPB   = 33554432;                // ushort NE
static constexpr size_t OFF_SPT   = 50331648;                // ushort NE   ([4][512][4096])
static constexpr size_t OFF_DBUF  = 67108864;                // float NE    (gxa / Sb / d1 / attn / rankp)
static constexpr size_t OFF_HBUF  = 100663296;               // float NE    (gaa / P / H)
static constexpr size_t OFF_GATB  = 134217728;               // ushort NE
static constexpr size_t OFF_NXB   = 150994944;               // ushort NE
static constexpr size_t OFF_EAB   = 167772160;               // ushort NE
static constexpr size_t OFF_AST   = 184549376;               // 512*512 ushort
static constexpr size_t OFF_WSP   = 185073664;
static constexpr size_t OFF_WSIL  = 185597952;
static constexpr size_t OFF_WOH   = 186122240;
static constexpr size_t OFF_WOUT  = 186646528;
static constexpr size_t OFF_WIGT  = 187170816;               // 4*128*128 ushort
static constexpr size_t OFF_WAGT  = 187301888;
static constexpr size_t OFF_POOL  = 187432960;               // 2048 uint
static constexpr size_t OFF_SCAL  = 187441152;               // 64 float
static constexpr size_t OFF_SCALI = 187441408;               // 64 int
static constexpr size_t OFF_BMAX  = 187441664;               // 2048 float
static constexpr size_t OFF_BIDX  = 187449856;               // 2048 int
static constexpr size_t OFF_SSP   = 187458048;               // 2048 float
static constexpr size_t OFF_COMB  = 187466240;               // 65536 float
static constexpr size_t OFF_VALS  = 187728384;
static constexpr size_t OFF_IMP   = 187990528;
static constexpr size_t OFF_GMOE  = 188252672;
static constexpr size_t OFF_SEL   = 188514816;
static constexpr size_t WS_NEED   = 188776960;

extern "C" void kernel_launch(void* const* d_in, const int* in_sizes, int n_in,
                              void* d_out, int out_size, void* d_ws, size_t ws_size,
                              hipStream_t stream)
{
    (void)in_sizes; (void)n_in; (void)out_size;
    const float* x    = (const float*)d_in[0];
    const float* AS   = (const float*)d_in[1];
    const float* Wsp  = (const float*)d_in[2];
    const float* Wsil = (const float*)d_in[3];
    const float* Woh  = (const float*)d_in[4];
    const float* Wout = (const float*)d_in[5];
    const float* wig  = (const float*)d_in[6];
    const float* wag  = (const float*)d_in[7];
    const float* a_param = (const float*)d_in[8];
    const float* cls_w = (const float*)d_in[9];
    const float* cls_b = (const float*)d_in[10];
    const float* tokw  = (const float*)d_in[11];
    const float* prelu = (const float*)d_in[12];
    const float* tsw   = (const float*)d_in[13];
    const float* tsa   = (const float*)d_in[14];
    const float* tsb   = (const float*)d_in[15];
    const float* tsmix = (const float*)d_in[16];
    const float* p1a = (const float*)d_in[17];
    const float* p1b = (const float*)d_in[18];
    const float* p1m = (const float*)d_in[19];
    const float* p2a = (const float*)d_in[20];
    const float* p2b = (const float*)d_in[21];
    const float* p2m = (const float*)d_in[22];
    float* out = (float*)d_out;

    char* w = (char*)d_ws;
    if (ws_size < WS_NEED) { sentinel_k<<<1, 256, 0, stream>>>(out); return; }

    ushort* xb    = (ushort*)(w + OFF_XB);
    ushort* tmpb  = (ushort*)(w + OFF_TMPB);
    ushort* spb   = (ushort*)(w + OFF_SPB);
    ushort* spT   = (ushort*)(w + OFF_SPT);
    float*  dbuf  = (float*)(w + OFF_DBUF);
    float*  Hbuf  = (float*)(w + OFF_HBUF);
    ushort* Sb    = (ushort*)(w + OFF_DBUF);   // alias
    ushort* Pb    = (ushort*)(w + OFF_HBUF);   // alias
    float*  gxa   = (float*)(w + OFF_DBUF);    // alias
    float*  gaa   = (float*)(w + OFF_HBUF);    // alias
    float*  pvpart= (float*)(w + OFF_XB);      // alias (32MB: XB+TMPB), used only during attention pool
    int*    rankp = (int*)(w + OFF_DBUF);      // alias (512KB), used only during ts2
    ushort* gatedb= (ushort*)(w + OFF_GATB);
    ushort* nxb   = (ushort*)(w + OFF_NXB);
    ushort* eab   = (ushort*)(w + OFF_EAB);
    ushort* ASt   = (ushort*)(w + OFF_AST);
    ushort* Wspb  = (ushort*)(w + OFF_WSP);
    ushort* Wsilb = (ushort*)(w + OFF_WSIL);
    ushort* Wohb  = (ushort*)(w + OFF_WOH);
    ushort* Woutb = (ushort*)(w + OFF_WOUT);
    ushort* wigT  = (ushort*)(w + OFF_WIGT);
    ushort* wagT  = (ushort*)(w + OFF_WAGT);
    uint*   poolU = (uint*)(w + OFF_POOL);
    float*  scal  = (float*)(w + OFF_SCAL);
    int*    scalI = (int*)(w + OFF_SCALI);
    float*  bmax  = (float*)(w + OFF_BMAX);
    int*    bidx  = (int*)(w + OFF_BIDX);
    float*  sspart= (float*)(w + OFF_SSP);
    float*  comb  = (float*)(w + OFF_COMB);
    float*  vals  = (float*)(w + OFF_VALS);
    float*  imp   = (float*)(w + OFF_IMP);
    float*  gmoe  = (float*)(w + OFF_GMOE);
    float*  sel   = (float*)(w + OFF_SEL);
    ushort* gsb     = tmpb;   // reuse (after attention pool)
    ushort* probs2b = xb;     // reuse (after attention pool)

    // ---- prep ----
    convert_f2b_k<<<2048, 256, 0, stream>>>(x, xb, NE >> 2);
    convert_f2b_k<<<64, 256, 0, stream>>>(Wsp, Wspb, 65536);
    convert_f2b_k<<<64, 256, 0, stream>>>(Wsil, Wsilb, 65536);
    convert_f2b_k<<<64, 256, 0, stream>>>(Woh, Wohb, 65536);
    convert_f2b_k<<<64, 256, 0, stream>>>(Wout, Woutb, 65536);
    transpose_to_bf16<true><<<dim3(16, 16, 1), 256, 0, stream>>>(AS, ASt, 512, 512);
    transpose_to_bf16<true><<<dim3(4, 4, 4), 256, 0, stream>>>(wig, wigT, 128, 128);
    transpose_to_bf16<true><<<dim3(4, 4, 4), 256, 0, stream>>>(wag, wagT, 128, 128);
    init_pool_k<<<8, 256, 0, stream>>>(poolU);

    // ---- G1: tmp = x @ AS ; G2: spatial = tmp @ Wsp^T ----
    gemm_bt<1><<<dim3(4, 128), 256, 0, stream>>>(xb, 512, ASt, 512, tmpb, 512, 512, nullptr);
    gemm_bt<1><<<dim3(4, 128), 256, 0, stream>>>(tmpb, 512, Wspb, 512, spb, 512, 512, nullptr);

    // ---- gates: batched block-diag GEMMs then elementwise ----
    gate_gemm_k<<<dim3(2, 128, 4), 256, 0, stream>>>(xb, wigT, wagT, gxa, gaa);
    gates_elem_k<<<2048, 256, 0, stream>>>(x, gxa, gaa, a_param, nxb, eab);

    // ---- attention pool (per batch) ----
    transpose_to_bf16<false><<<dim3(16, 128, 4), 256, 0, stream>>>(spb, spT, 4096, 512);
    const float sc128 = 0.0883883476f;
    for (int b = 0; b < 4; b++) {
        const ushort* spB = spb + (size_t)b * L_ * D_;
        gemm_bt<1><<<dim3(32, 32), 256, 0, stream>>>(spB, 512, spB, 512, Sb, 4096, 512, nullptr);
        softmax_rows_k<<<4096, 256, 0, stream>>>(Sb, Pb, sc128);
        pv_split_k<<<dim3(4, 32, 4), 256, 0, stream>>>(Pb, spT + (size_t)b * D_ * L_, pvpart);
        pool_combine_k<<<128, 256, 0, stream>>>(pvpart, poolU + b * 512);
    }

    // ---- gated = exp(log_a)*pool + nx ----
    gated_k<<<1024, 256, 0, stream>>>(eab, nxb, poolU, gatedb);

    // ---- sparsity = ripple_act(gated @ Wsil^T) ; gs = gated * sparsity ----
    gemm_bt<0><<<dim3(4, 128), 256, 0, stream>>>(gatedb, 512, Wsilb, 512, dbuf, 512, 512, nullptr);
    redmax1_k<<<1024, 256, 0, stream>>>(dbuf, NE, bmax, bidx);
    redmax2_k<<<1, 256, 0, stream>>>(bmax, bidx, 1024, &scal[0], &scalI[0]);
    ripple_g_k<<<2048, 256, 0, stream>>>(dbuf, Hbuf, sspart, &scal[0], p1a, p1b, p1m);
    redsum2_k<<<1, 256, 0, stream>>>(sspart, 2048, &scal[1]);
    ripple_softmax_k<1><<<16384, 256, 0, stream>>>(Hbuf, &scal[0], &scalI[0], &scal[1], p1a, gatedb, gsb);

    // ---- token selection -> sel ----
    ts1_k<<<4096, 256, 0, stream>>>(x, cls_w, cls_b, tokw, prelu, comb, vals);
    ts2a_k<<<dim3(16, 8, 4), 256, 0, stream>>>(comb, rankp);
    ts2b_k<<<dim3(16, 4), 256, 0, stream>>>(rankp, vals, imp);
    redmax1_k<<<64, 256, 0, stream>>>(imp, 65536, bmax, bidx);
    redmax2_k<<<1, 256, 0, stream>>>(bmax, bidx, 64, &scal[4], &scalI[2]);
    moe_g_k<<<64, 256, 0, stream>>>(imp, gmoe, sspart, &scal[4], tsw, tsa, tsb, tsmix);
    redsum2_k<<<1, 256, 0, stream>>>(sspart, 64, &scal[5]);
    moe_sel_k<<<4, 256, 0, stream>>>(gmoe, &scal[4], &scalI[2], &scal[5], sel);

    // ---- attn = gs @ Woh^T, scaled by sel ----
    gemm_bt<3><<<dim3(4, 128), 256, 0, stream>>>(gsb, 512, Wohb, 512, dbuf, 512, 512, sel);

    // ---- out_probs = ripple_act(d2) ----
    redmax1_k<<<1024, 256, 0, stream>>>(dbuf, NE, bmax, bidx);
    redmax2_k<<<1, 256, 0, stream>>>(bmax, bidx, 1024, &scal[2], &scalI[1]);
    ripple_g_k<<<2048, 256, 0, stream>>>(dbuf, Hbuf, sspart, &scal[2], p2a, p2b, p2m);
    redsum2_k<<<1, 256, 0, stream>>>(sspart, 2048, &scal[3]);
    ripple_softmax_k<0><<<16384, 256, 0, stream>>>(Hbuf, &scal[2], &scalI[1], &scal[3], p2a, nullptr, probs2b);

    // ---- out = probs @ Wout^T ----
    gemm_bt<0><<<dim3(4, 128), 256, 0, stream>>>(probs2b, 512, Woutb, 512, out, 512, 512, nullptr);
}

// Round 5
// 641.641 us; speedup vs baseline: 6.4664x; 1.1318x over previous
//
#include <hip/hip_runtime.h>

typedef unsigned short ushort;
typedef unsigned int uint;
typedef unsigned long long u64;

#define DEV __device__ __forceinline__

typedef __attribute__((ext_vector_type(4))) float f32x4;
typedef __bf16 bf16x8 __attribute__((ext_vector_type(8)));
typedef __attribute__((ext_vector_type(4))) ushort u16x4;
typedef __attribute__((ext_vector_type(8))) ushort u16x8;

static constexpr int B_ = 4, L_ = 4096, D_ = 512;
static constexpr long NE = (long)B_ * L_ * D_;      // 8388608

// ---------------- small helpers ----------------
DEV float b2f(ushort u) { return __uint_as_float(((uint)u) << 16); }
DEV ushort f2b(float f) {
    uint u = __float_as_uint(f);
    uint r = u + 0x7FFFu + ((u >> 16) & 1u);
    return (ushort)(r >> 16);
}
DEV uint mapF(float f) {
    uint b = __float_as_uint(f);
    return (b & 0x80000000u) ? ~b : (b | 0x80000000u);
}
DEV float unmapF(uint u) {
    uint b = (u & 0x80000000u) ? (u & 0x7FFFFFFFu) : ~u;
    return __uint_as_float(b);
}
DEV float rcp_(float x) { return __builtin_amdgcn_rcpf(x); }
DEV float fexp(float x) { return __builtin_amdgcn_exp2f(x * 1.44269504089f); }
DEV float sigm(float x) { return rcp_(1.f + fexp(-x)); }

// async global->LDS, 16B per lane, wave-uniform LDS base
DEV void gload16(const ushort* g, ushort* l) {
    __builtin_amdgcn_global_load_lds((const __attribute__((address_space(1))) void*)g,
                                     (__attribute__((address_space(3))) void*)l, 16, 0, 0);
}

// trigamma(t+1), t in (-1,1): 6-term shifted series + asymptotic, fast rcp
DEV float trigamma1p(float t) {
    float x = t + 1.f;
    float acc = 0.f;
#pragma unroll
    for (int k = 0; k < 6; k++) { float xx = x + (float)k; acc += rcp_(xx * xx); }
    float y = x + 6.f;
    float iy = rcp_(y), iy2 = iy * iy;
    return acc + iy * (1.f + iy * (0.5f + iy * (0.166666667f + iy2 * (-0.0333333333f + iy2 * 0.0238095238f))));
}
// I1(t), |t|<~1.2: power series
DEV float besselI1(float t) {
    float q = 0.25f * t * t;
    return 0.5f * t * (1.f + q * (0.5f + q * (0.0833333333f + q * (0.00694444444f + q * (3.47222222e-4f + q * 1.15740741e-5f)))));
}
DEV float rippleH(float u, float beta, float mix0, float mix1) {
    float t = beta * erff(u);
    float Tp = mix0 * trigamma1p(t) + mix1 * besselI1(t);
    float ep = 1.12837917f * fexp(-u * u);
    return beta * Tp * ep;
}

// ---------------- shared GEMM core: 128x128 tile, K-loop, bf16 MFMA ----------------
DEV void gemm_core(const ushort* __restrict__ A, int lda,
                   const ushort* __restrict__ Bt, int ldb, int K,
                   ushort* __restrict__ Alds, ushort* __restrict__ Blds,
                   f32x4 (&acc)[4][4])
{
    const int tid = threadIdx.x;
    const int lane = tid & 63;
    const int wave = tid >> 6;
    const int wr = wave >> 1, wc = wave & 1;

    const int srow = wave * 16 + (lane >> 2);
    const int skc = (lane & 3) * 8;
    const ushort* Ag0 = A + (size_t)srow * lda + skc;
    const ushort* Ag1 = A + (size_t)(srow + 64) * lda + skc;
    const ushort* Bg0 = Bt + (size_t)srow * ldb + skc;
    const ushort* Bg1 = Bt + (size_t)(srow + 64) * ldb + skc;
    ushort* Al0 = Alds + wave * 512;          // wave-uniform LDS bases
    ushort* Al1 = Alds + 2048 + wave * 512;
    ushort* Bl0 = Blds + wave * 512;
    ushort* Bl1 = Blds + 2048 + wave * 512;

    const int ar = wr * 64 + (lane & 15);
    const int br = wc * 64 + (lane & 15);
    const int kk = (lane >> 4) * 8;

    for (int k0 = 0; k0 < K; k0 += 32) {
        __syncthreads();
        gload16(Ag0 + k0, Al0);
        gload16(Ag1 + k0, Al1);
        gload16(Bg0 + k0, Bl0);
        gload16(Bg1 + k0, Bl1);
        __syncthreads();
        bf16x8 af[4], bfr[4];
#pragma unroll
        for (int mi = 0; mi < 4; mi++) af[mi] = *(const bf16x8*)&Alds[(ar + mi * 16) * 32 + kk];
#pragma unroll
        for (int ni = 0; ni < 4; ni++) bfr[ni] = *(const bf16x8*)&Blds[(br + ni * 16) * 32 + kk];
#pragma unroll
        for (int mi = 0; mi < 4; mi++)
#pragma unroll
            for (int ni = 0; ni < 4; ni++)
                acc[mi][ni] = __builtin_amdgcn_mfma_f32_16x16x32_bf16(af[mi], bfr[ni], acc[mi][ni], 0, 0, 0);
    }
}

// ---------------- GEMM: C[M,N] = A[M,K] * Bt[N,K]^T ----------------
// MODE 0: f32 out; 1: bf16 out; 3: f32 out scaled by rowScale[global row]
// DOMAX: fused global max+argmax (first-index tie-break) via packed u64 atomicMax
template <int MODE, bool DOMAX>
__global__ __launch_bounds__(256, 2) void gemm_bt(
    const ushort* __restrict__ A, int lda,
    const ushort* __restrict__ Bt, int ldb,
    void* __restrict__ Cv, int ldc, int K,
    const float* __restrict__ rowScale, u64* __restrict__ pmax)
{
    __shared__ ushort Alds[128 * 32];
    __shared__ ushort Blds[128 * 32];
    const int row0 = blockIdx.y * 128, col0 = blockIdx.x * 128;
    f32x4 acc[4][4] = {};
    gemm_core(A + (size_t)row0 * lda, lda, Bt + (size_t)col0 * ldb, ldb, K, Alds, Blds, acc);

    const int tid = threadIdx.x;
    const int lane = tid & 63;
    const int wave = tid >> 6;
    const int wr = wave >> 1, wc = wave & 1;
    const int ocol = col0 + wc * 64 + (lane & 15);
    u64 lp = 0;
#pragma unroll
    for (int mi = 0; mi < 4; mi++) {
        const int rbase = row0 + wr * 64 + mi * 16 + (lane >> 4) * 4;
#pragma unroll
        for (int j = 0; j < 4; j++) {
            float sc = (MODE == 3) ? rowScale[rbase + j] : 1.f;
#pragma unroll
            for (int ni = 0; ni < 4; ni++) {
                float v = acc[mi][ni][j] * sc;
                int cc = ocol + ni * 16;
                if (MODE == 1) ((ushort*)Cv)[(size_t)(rbase + j) * ldc + cc] = f2b(v);
                else ((float*)Cv)[(size_t)(rbase + j) * ldc + cc] = v;
                if (DOMAX) {
                    uint idx = (uint)((rbase + j) * ldc + cc);
                    u64 p = ((u64)mapF(v) << 32) | (u64)(~idx);
                    lp = (p > lp) ? p : lp;
                }
            }
        }
    }
    if (DOMAX) {
#pragma unroll
        for (int off = 32; off > 0; off >>= 1) {
            u64 o = __shfl_xor(lp, off);
            lp = (o > lp) ? o : lp;
        }
        if (lane == 0) atomicMax(pmax, lp);
    }
}

// ---------------- PV split-K: part[ks][4096][512] = P[:, ks*1024:(ks+1)*1024] @ V ----------------
__global__ __launch_bounds__(256, 2) void pv_split_k(const ushort* __restrict__ P, const ushort* __restrict__ Vt,
                                                     float* __restrict__ part)
{
    __shared__ ushort Alds[128 * 32];
    __shared__ ushort Blds[128 * 32];
    const int ks = blockIdx.z;
    const int row0 = blockIdx.y * 128, col0 = blockIdx.x * 128;
    f32x4 acc[4][4] = {};
    gemm_core(P + (size_t)row0 * 4096 + ks * 1024, 4096,
              Vt + (size_t)col0 * 4096 + ks * 1024, 4096, 1024, Alds, Blds, acc);

    float* C = part + (size_t)ks * 2097152 + (size_t)row0 * 512 + col0;
    const int tid = threadIdx.x;
    const int lane = tid & 63;
    const int wave = tid >> 6;
    const int wr = wave >> 1, wc = wave & 1;
    const int ocol = wc * 64 + (lane & 15);
#pragma unroll
    for (int mi = 0; mi < 4; mi++) {
        const int rl = wr * 64 + mi * 16 + (lane >> 4) * 4;
#pragma unroll
        for (int j = 0; j < 4; j++)
#pragma unroll
            for (int ni = 0; ni < 4; ni++)
                C[(size_t)(rl + j) * 512 + ocol + ni * 16] = acc[mi][ni][j];
    }
}

// combine: pool[d] = max over l of sum_ks part[ks][l][d]; 128 blocks x 32 rows
__global__ __launch_bounds__(256) void pool_combine_k(const float* __restrict__ part, uint* __restrict__ poolU)
{
    const int tid = threadIdx.x;
    const int l0 = blockIdx.x * 32;
    float m0 = -3.4e38f, m1 = -3.4e38f;
    for (int l = 0; l < 32; l++) {
        size_t off = (size_t)(l0 + l) * 512;
        float s0 = 0.f, s1 = 0.f;
#pragma unroll
        for (int ks = 0; ks < 4; ks++) {
            s0 += part[(size_t)ks * 2097152 + off + tid];
            s1 += part[(size_t)ks * 2097152 + off + tid + 256];
        }
        m0 = fmaxf(m0, s0); m1 = fmaxf(m1, s1);
    }
    atomicMax(&poolU[tid], mapF(m0));
    atomicMax(&poolU[tid + 256], mapF(m1));
}

// ---------------- batched block-diag gate GEMMs: grid (2, 128, 4), bf16 out ----------------
__global__ __launch_bounds__(256, 2) void gate_gemm_k(const ushort* __restrict__ xb,
                                                      const ushort* __restrict__ wigT, const ushort* __restrict__ wagT,
                                                      ushort* __restrict__ gxab, ushort* __restrict__ gaab)
{
    __shared__ ushort Alds[128 * 32];
    __shared__ ushort Blds[128 * 32];
    const int which = blockIdx.x;
    const int h = blockIdx.z;
    const ushort* A = xb + (size_t)blockIdx.y * 128 * 512 + h * 128;
    const ushort* W = (which ? wagT : wigT) + (size_t)h * 16384;
    f32x4 acc[4][4] = {};
    gemm_core(A, 512, W, 128, 128, Alds, Blds, acc);

    ushort* C = (which ? gaab : gxab) + (size_t)blockIdx.y * 128 * 512 + h * 128;
    const int tid = threadIdx.x;
    const int lane = tid & 63;
    const int wave = tid >> 6;
    const int wr = wave >> 1, wc = wave & 1;
    const int ocol = wc * 64 + (lane & 15);
#pragma unroll
    for (int mi = 0; mi < 4; mi++) {
        const int rl = wr * 64 + mi * 16 + (lane >> 4) * 4;
#pragma unroll
        for (int j = 0; j < 4; j++)
#pragma unroll
            for (int ni = 0; ni < 4; ni++)
                C[(size_t)(rl + j) * 512 + ocol + ni * 16] = f2b(acc[mi][ni][j]);
    }
}

// ---------------- misc kernels ----------------
__global__ void convert_f2b_k(const float* __restrict__ s, ushort* __restrict__ d, long n4) {
    long i = (long)blockIdx.x * blockDim.x + threadIdx.x;
    long st = (long)gridDim.x * blockDim.x;
    for (; i < n4; i += st) {
        f32x4 v = ((const f32x4*)s)[i];
        u16x4 o;
        o[0] = f2b(v[0]); o[1] = f2b(v[1]); o[2] = f2b(v[2]); o[3] = f2b(v[3]);
        ((u16x4*)d)[i] = o;
    }
}

// 4 weight matrices (512x512 each) in one launch; dsts contiguous at Wspb
__global__ void convert_w4_k(const float* __restrict__ w0, const float* __restrict__ w1,
                             const float* __restrict__ w2, const float* __restrict__ w3,
                             ushort* __restrict__ dst) {
    const float* srcs[4] = {w0, w1, w2, w3};
    const float* s = srcs[blockIdx.y];
    ushort* d = dst + (size_t)blockIdx.y * 262144;
    int i = blockIdx.x * 256 + threadIdx.x;   // 0..65535 (x4 elems)
    f32x4 v = ((const f32x4*)s)[i];
    u16x4 o;
    o[0] = f2b(v[0]); o[1] = f2b(v[1]); o[2] = f2b(v[2]); o[3] = f2b(v[3]);
    ((u16x4*)d)[i] = o;
}

template <bool SRCF32>
__global__ __launch_bounds__(256) void transpose_to_bf16(const void* __restrict__ srcv, ushort* __restrict__ dst, int R, int C) {
    __shared__ float tile[32][33];
    const int z = blockIdx.z;
    const float* sf = (const float*)srcv + (size_t)z * R * C;
    const ushort* sb = (const ushort*)srcv + (size_t)z * R * C;
    ushort* dz = dst + (size_t)z * R * C;
    const int tx = threadIdx.x & 31, ty = threadIdx.x >> 5;
    const int c = blockIdx.x * 32 + tx;
#pragma unroll
    for (int k = 0; k < 4; k++) {
        const int r = blockIdx.y * 32 + ty + k * 8;
        tile[ty + k * 8][tx] = SRCF32 ? sf[(size_t)r * C + c] : b2f(sb[(size_t)r * C + c]);
    }
    __syncthreads();
#pragma unroll
    for (int k = 0; k < 4; k++) {
        const int dr = blockIdx.x * 32 + ty + k * 8;
        const int dc = blockIdx.y * 32 + tx;
        dz[(size_t)dr * R + dc] = f2b(tile[tx][ty + k * 8]);
    }
}

// wig+wag transposes in one launch: z = 0..7 -> (which = z>>2, h = z&3), 128x128 each
__global__ __launch_bounds__(256) void transpose_gates_k(const float* __restrict__ wig, const float* __restrict__ wag,
                                                         ushort* __restrict__ wigT, ushort* __restrict__ wagT) {
    __shared__ float tile[32][33];
    const int which = blockIdx.z >> 2, h = blockIdx.z & 3;
    const float* src = (which ? wag : wig) + (size_t)h * 16384;
    ushort* dst = (which ? wagT : wigT) + (size_t)h * 16384;
    const int tx = threadIdx.x & 31, ty = threadIdx.x >> 5;
    const int c = blockIdx.x * 32 + tx;
#pragma unroll
    for (int k = 0; k < 4; k++) {
        const int r = blockIdx.y * 32 + ty + k * 8;
        tile[ty + k * 8][tx] = src[(size_t)r * 128 + c];
    }
    __syncthreads();
#pragma unroll
    for (int k = 0; k < 4; k++) {
        const int dr = blockIdx.x * 32 + ty + k * 8;
        const int dc = blockIdx.y * 32 + tx;
        dst[(size_t)dr * 128 + dc] = f2b(tile[tx][ty + k * 8]);
    }
}

__global__ void init_misc_k(uint* poolU, u64* pmax) {
    int i = blockIdx.x * 256 + threadIdx.x;
    if (i < 2048) poolU[i] = 0u;
    if (i < 4) pmax[i] = 0ull;
}
__global__ void sentinel_k(float* o) { o[threadIdx.x] = 1.0e6f; }

// fused gates+gated (post-pool): gated = exp(la)*pool + x*sigm(gx)*sqrt(1-exp(2la))
__global__ __launch_bounds__(256) void gates_gated_k(const float* __restrict__ x, const ushort* __restrict__ gxab,
                                                     const ushort* __restrict__ gaab, const float* __restrict__ a_param,
                                                     const uint* __restrict__ poolU, ushort* __restrict__ gatedb) {
    __shared__ float sp8[512];
    const int tid = threadIdx.x;
    for (int d = tid; d < 512; d += 256) {
        float a = a_param[d];
        sp8[d] = 8.f * (fmaxf(a, 0.f) + log1pf(expf(-fabsf(a))));
    }
    __syncthreads();
    long i = (long)blockIdx.x * blockDim.x + tid;
    long st = (long)gridDim.x * blockDim.x;
    const long n8 = NE >> 3;
    for (; i < n8; i += st) {
        u16x8 gx8 = ((const u16x8*)gxab)[i];
        u16x8 ga8 = ((const u16x8*)gaab)[i];
        f32x4 x0 = ((const f32x4*)x)[2 * i];
        f32x4 x1 = ((const f32x4*)x)[2 * i + 1];
        long e = i << 3;
        int b = (int)(e >> 21);
        int d0 = (int)(e & 511);
        u16x8 o;
#pragma unroll
        for (int j = 0; j < 8; j++) {
            float xv = (j < 4) ? x0[j] : x1[j - 4];
            float gx = sigm(b2f(gx8[j]));
            float ga = sigm(b2f(ga8[j]));
            float la = -sp8[d0 + j] * ga;
            float ea = fexp(la);
            float nx = xv * gx * sqrtf(fmaxf(1.f - fexp(2.f * la), 0.f));
            float pl = unmapF(poolU[b * 512 + d0 + j]);
            o[j] = f2b(ea * pl + nx);
        }
        ((u16x8*)gatedb)[i] = o;
    }
}

// row softmax over N=4096 bf16 -> bf16
__global__ __launch_bounds__(256) void softmax_rows_k(const ushort* __restrict__ S, ushort* __restrict__ P, float scale) {
    __shared__ float red[256];
    const int tid = threadIdx.x;
    const ushort* row = S + (size_t)blockIdx.x * 4096;
    float vals[16];
    bf16x8 v0 = *(const bf16x8*)&row[tid * 16];
    bf16x8 v1 = *(const bf16x8*)&row[tid * 16 + 8];
    float mx = -3.4e38f;
#pragma unroll
    for (int k = 0; k < 8; k++) { vals[k] = (float)v0[k] * scale; mx = fmaxf(mx, vals[k]); }
#pragma unroll
    for (int k = 0; k < 8; k++) { vals[8 + k] = (float)v1[k] * scale; mx = fmaxf(mx, vals[8 + k]); }
    red[tid] = mx; __syncthreads();
    for (int s = 128; s > 0; s >>= 1) { if (tid < s) red[tid] = fmaxf(red[tid], red[tid + s]); __syncthreads(); }
    mx = red[0]; __syncthreads();
    float sum = 0.f;
#pragma unroll
    for (int k = 0; k < 16; k++) { vals[k] = fexp(vals[k] - mx); sum += vals[k]; }
    red[tid] = sum; __syncthreads();
    for (int s = 128; s > 0; s >>= 1) { if (tid < s) red[tid] += red[tid + s]; __syncthreads(); }
    float inv = rcp_(red[0]);
    ushort* prow = P + (size_t)blockIdx.x * 4096;
#pragma unroll
    for (int k = 0; k < 16; k++) prow[tid * 16 + k] = f2b(vals[k] * inv);
}

// global max + argmax (stage1), n elements (used for moe over imp)
__global__ __launch_bounds__(256) void redmax1_k(const float* __restrict__ d, long n, float* __restrict__ bmax, int* __restrict__ bidx) {
    __shared__ float rv[256];
    __shared__ int ri[256];
    const int tid = threadIdx.x;
    long g = (long)blockIdx.x * 256 + tid;
    const long stride = (long)gridDim.x * 256;
    float bv = -3.4e38f; int bi = -1;
    for (long i = g; i < n; i += stride) {
        float v = d[i];
        if (v > bv) { bv = v; bi = (int)i; }
    }
    rv[tid] = bv; ri[tid] = bi; __syncthreads();
    for (int s = 128; s > 0; s >>= 1) {
        if (tid < s) {
            float ov = rv[tid + s]; int oi = ri[tid + s];
            if (oi >= 0 && (ri[tid] < 0 || ov > rv[tid] || (ov == rv[tid] && oi < ri[tid]))) { rv[tid] = ov; ri[tid] = oi; }
        }
        __syncthreads();
    }
    if (tid == 0) { bmax[blockIdx.x] = rv[0]; bidx[blockIdx.x] = ri[0]; }
}
__global__ __launch_bounds__(256) void redmax2_k(const float* __restrict__ bmax, const int* __restrict__ bidx, int n,
                                                 float* __restrict__ outM, int* __restrict__ outI) {
    __shared__ float rv[256];
    __shared__ int ri[256];
    const int tid = threadIdx.x;
    float bv = -3.4e38f; int bi = -1;
    for (int i = tid; i < n; i += 256) {
        float v = bmax[i]; int ix = bidx[i];
        if (ix >= 0 && (bi < 0 || v > bv || (v == bv && ix < bi))) { bv = v; bi = ix; }
    }
    rv[tid] = bv; ri[tid] = bi; __syncthreads();
    for (int s = 128; s > 0; s >>= 1) {
        if (tid < s) {
            float ov = rv[tid + s]; int oi = ri[tid + s];
            if (oi >= 0 && (ri[tid] < 0 || ov > rv[tid] || (ov == rv[tid] && oi < ri[tid]))) { rv[tid] = ov; ri[tid] = oi; }
        }
        __syncthreads();
    }
    if (tid == 0) { outM[0] = rv[0]; outI[0] = ri[0]; }
}

// ripple gradient base; M from packed pmax
__global__ __launch_bounds__(256) void ripple_g_k(const float* __restrict__ d, float* __restrict__ gb, float* __restrict__ sspart,
                                                  const u64* __restrict__ pmax, const float* __restrict__ alpha_p,
                                                  const float* __restrict__ beta_p, const float* __restrict__ mix_p) {
    __shared__ float red[256];
    const int tid = threadIdx.x;
    const float M = unmapF((uint)(pmax[0] >> 32));
    const float alpha = alpha_p[0], beta = beta_p[0];
    float m0 = mix_p[0], m1 = mix_p[1];
    float mm = fmaxf(m0, m1);
    float e0 = fexp(m0 - mm), e1 = fexp(m1 - mm);
    float inv = rcp_(e0 + e1);
    float mix0 = e0 * inv, mix1 = e1 * inv;
    const float invMA = rcp_(M * alpha);
    float ss = 0.f;
    long g = (long)blockIdx.x * 256 + tid;
    const long stride = (long)gridDim.x * 256;
    for (long i = g; i < NE; i += stride) {
        float dv = d[i];
        float H = rippleH(dv * invMA, beta, mix0, mix1);
        gb[i] = H * invMA;
        ss += H * dv;
    }
    red[tid] = ss; __syncthreads();
    for (int s = 128; s > 0; s >>= 1) { if (tid < s) red[tid] += red[tid + s]; __syncthreads(); }
    if (tid == 0) sspart[blockIdx.x] = red[0];
}
__global__ __launch_bounds__(256) void redsum2_k(const float* __restrict__ part, int n, float* __restrict__ out) {
    __shared__ float red[256];
    const int tid = threadIdx.x;
    float s = 0.f;
    for (int i = tid; i < n; i += 256) s += part[i];
    red[tid] = s; __syncthreads();
    for (int q = 128; q > 0; q >>= 1) { if (tid < q) red[tid] += red[tid + q]; __syncthreads(); }
    if (tid == 0) out[0] = red[0];
}

// per-row (512) softmin; amax from packed pmax
template <int GS>
__global__ __launch_bounds__(256) void ripple_softmax_k(const float* __restrict__ gb,
                                                        const u64* __restrict__ pmax,
                                                        const float* __restrict__ ssTot, const float* __restrict__ alpha_p,
                                                        const ushort* __restrict__ gatedb, ushort* __restrict__ outb) {
    __shared__ float red[256];
    const int tid = threadIdx.x;
    const float M = unmapF((uint)(pmax[0] >> 32));
    const int amax = (int)(~(uint)(pmax[0] & 0xFFFFFFFFull));
    const float corr = ssTot[0] * rcp_(M * M * alpha_p[0]);
    long base = (long)blockIdx.x * 512;
    float g0 = gb[base + tid];
    float g1 = gb[base + tid + 256];
    if ((int)(base + tid) == amax) g0 -= corr;
    if ((int)(base + tid + 256) == amax) g1 -= corr;
    g0 = fminf(fmaxf(g0, -1.f), 1.f);
    g1 = fminf(fmaxf(g1, -1.f), 1.f);
    float mn = fminf(g0, g1);
    red[tid] = mn; __syncthreads();
    for (int s = 128; s > 0; s >>= 1) { if (tid < s) red[tid] = fminf(red[tid], red[tid + s]); __syncthreads(); }
    mn = red[0]; __syncthreads();
    float e0 = fexp(mn - g0), e1 = fexp(mn - g1);
    red[tid] = e0 + e1; __syncthreads();
    for (int s = 128; s > 0; s >>= 1) { if (tid < s) red[tid] += red[tid + s]; __syncthreads(); }
    float inv = rcp_(red[0]);
    if (GS) {
        outb[base + tid] = f2b(b2f(gatedb[base + tid]) * (e0 * inv));
        outb[base + tid + 256] = f2b(b2f(gatedb[base + tid + 256]) * (e1 * inv));
    } else {
        outb[base + tid] = f2b(e0 * inv);
        outb[base + tid + 256] = f2b(e1 * inv);
    }
}

// token selection stage 1
__global__ __launch_bounds__(256) void ts1_k(const float* __restrict__ x, const float* __restrict__ cls_w,
                                             const float* __restrict__ cls_b, const float* __restrict__ tw,
                                             const float* __restrict__ prelu_a,
                                             float* __restrict__ combined, float* __restrict__ vals) {
    __shared__ float cw[2048];
    const int tid = threadIdx.x;
    for (int i = tid; i < 2048; i += 256) cw[i] = cls_w[i];
    __syncthreads();
    const int lane = tid & 63, wid = tid >> 6;
    const int row = blockIdx.x * 4 + wid;
    const float* xr = x + (size_t)row * 512 + lane * 8;
    float pa0 = 0, pa1 = 0, pa2 = 0, pa3 = 0;
#pragma unroll
    for (int j = 0; j < 8; j++) {
        float v = xr[j];
        int c = lane * 8 + j;
        pa0 += v * cw[c]; pa1 += v * cw[512 + c]; pa2 += v * cw[1024 + c]; pa3 += v * cw[1536 + c];
    }
#pragma unroll
    for (int o = 32; o > 0; o >>= 1) {
        pa0 += __shfl_down(pa0, o); pa1 += __shfl_down(pa1, o);
        pa2 += __shfl_down(pa2, o); pa3 += __shfl_down(pa3, o);
    }
    if (lane == 0) {
        float a = prelu_a[0];
        float sc[4] = {pa0, pa1, pa2, pa3};
        float comb = 0.f, vsum = 0.f;
#pragma unroll
        for (int s = 0; s < 4; s++) {
            float p = sc[s] + cls_b[s];
            p = (p >= 0.f) ? p : a * p;
            float cel = (p > 0.f) ? p : expm1f(p);
            float sil = p * sigm(p);
            float gel = 0.5f * p * (1.f + erff(p * 0.70710678f));
            float ts = cel * sil + gel;
            float ww = tw[s];
            float se = 1.05070099f * ((ww > 0.f) ? ww : 1.67326324f * expm1f(ww));
            comb += se * ts;
            vsum += ts;
        }
        combined[row] = comb;
        vals[row] = vsum;
    }
}

// ts2a: partial ranks. grid (16 p-chunks, 8 q-chunks, 4 batches)
__global__ __launch_bounds__(256) void ts2a_k(const float* __restrict__ combined, int* __restrict__ rankp) {
    __shared__ float q[512];
    const int b = blockIdx.z;
    const int tid = threadIdx.x;
    const float* cr = combined + b * 4096;
    const int q0 = blockIdx.y * 512;
    for (int i = tid; i < 512; i += 256) q[i] = cr[q0 + i];
    __syncthreads();
    const int p = blockIdx.x * 256 + tid;
    const float cp = cr[p];
    const f32x4* q4 = (const f32x4*)q;
    int rank = 0;
#pragma unroll 8
    for (int i4 = 0; i4 < 128; i4++) {
        f32x4 v = q4[i4];
        int qb = q0 + i4 * 4;
        rank += (v[0] > cp) || (v[0] == cp && (qb + 0) < p);
        rank += (v[1] > cp) || (v[1] == cp && (qb + 1) < p);
        rank += (v[2] > cp) || (v[2] == cp && (qb + 2) < p);
        rank += (v[3] > cp) || (v[3] == cp && (qb + 3) < p);
    }
    rankp[((b * 8 + blockIdx.y) * 4096) + p] = rank;
}

// ts2b: gather. grid (16, 4)
__global__ __launch_bounds__(256) void ts2b_k(const int* __restrict__ rankp, const float* __restrict__ vals,
                                              float* __restrict__ imp) {
    const int b = blockIdx.y;
    const int p = blockIdx.x * 256 + threadIdx.x;
    int rank = 0;
#pragma unroll
    for (int c = 0; c < 8; c++) rank += rankp[((b * 8 + c) * 4096) + p];
    imp[b * 4096 + p] = 1.f + vals[b * 4096 + rank];
}

// moe gradient base over n=65536
__global__ __launch_bounds__(256) void moe_g_k(const float* __restrict__ imp, float* __restrict__ gmoe,
                                               float* __restrict__ sspart, const float* __restrict__ scalM,
                                               const float* __restrict__ tsw, const float* __restrict__ tsa,
                                               const float* __restrict__ tsb, const float* __restrict__ tsmix) {
    __shared__ float red[256];
    const int tid = threadIdx.x;
    const float M = scalM[0];
    float w[4], invMA[4], invA[4];
    {
        float wm = fmaxf(fmaxf(tsw[0], tsw[1]), fmaxf(tsw[2], tsw[3]));
        float s = 0.f;
#pragma unroll
        for (int k = 0; k < 4; k++) { w[k] = fexp(tsw[k] - wm); s += w[k]; }
        float si = rcp_(s);
#pragma unroll
        for (int k = 0; k < 4; k++) { w[k] *= si; invMA[k] = rcp_(M * tsa[k]); invA[k] = rcp_(tsa[k]); }
    }
    const float beta = tsb[0];
    float m0 = tsmix[0], m1 = tsmix[1];
    float mm = fmaxf(m0, m1);
    float e0 = fexp(m0 - mm), e1 = fexp(m1 - mm);
    float minv = rcp_(e0 + e1);
    const float mix0 = e0 * minv, mix1 = e1 * minv;

    float ss = 0.f;
    int i = blockIdx.x * 256 + tid;
    const int stride = gridDim.x * 256;
    for (; i < 65536; i += stride) {
        float dv = imp[i];
        float gbv = 0.f;
#pragma unroll
        for (int s = 0; s < 4; s++) {
            float H = rippleH(dv * invMA[s], beta, mix0, mix1);
            gbv += w[s] * H * invMA[s];
            ss += w[s] * H * dv * invA[s];
        }
        gmoe[i] = gbv;
    }
    red[tid] = ss; __syncthreads();
    for (int s = 128; s > 0; s >>= 1) { if (tid < s) red[tid] += red[tid + s]; __syncthreads(); }
    if (tid == 0) sspart[blockIdx.x] = red[0];
}

// moe softmin per batch row (4096): sel = 1 + softmax(-clip(g - amax_corr))
__global__ __launch_bounds__(256) void moe_sel_k(const float* __restrict__ gmoe, const float* __restrict__ scalM,
                                                 const int* __restrict__ scalI, const float* __restrict__ ssTot,
                                                 float* __restrict__ sel) {
    __shared__ float red[256];
    const int tid = threadIdx.x;
    const int b = blockIdx.x;
    const float M = scalM[0];
    const int amax = scalI[0];
    const float corr = ssTot[0] * rcp_(M * M);
    float g[16];
    float mn = 3.4e38f;
#pragma unroll
    for (int k = 0; k < 16; k++) {
        int i = b * 4096 + tid + k * 256;
        float v = gmoe[i];
        if (i == amax) v -= corr;
        v = fminf(fmaxf(v, -1.f), 1.f);
        g[k] = v;
        mn = fminf(mn, v);
    }
    red[tid] = mn; __syncthreads();
    for (int s = 128; s > 0; s >>= 1) { if (tid < s) red[tid] = fminf(red[tid], red[tid + s]); __syncthreads(); }
    mn = red[0]; __syncthreads();
    float sum = 0.f;
#pragma unroll
    for (int k = 0; k < 16; k++) { g[k] = fexp(mn - g[k]); sum += g[k]; }
    red[tid] = sum; __syncthreads();
    for (int s = 128; s > 0; s >>= 1) { if (tid < s) red[tid] += red[tid + s]; __syncthreads(); }
    float inv = rcp_(red[0]);
#pragma unroll
    for (int k = 0; k < 16; k++) sel[b * 4096 + tid + k * 256] = 1.f + g[k] * inv;
}

// ---------------- workspace layout (bytes) ----------------
static constexpr size_t OFF_XB    = 0;                       // ushort NE (also: PV partials f32 32MB; later probs2b)
static constexpr size_t OFF_TMPB  = 16777216;                // ushort NE (later: gsb)
static constexpr size_t OFF_SPB   = 33554432;                // ushort NE
static constexpr size_t OFF_SPT   = 50331648;                // ushort NE   ([4][512][4096])
static constexpr size_t OFF_DBUF  = 67108864;                // float NE    (Sb / d1 / attn / rankp)
static constexpr size_t OFF_HBUF  = 100663296;               // float NE    (Pb / H)
static constexpr size_t OFF_GATB  = 134217728;               // ushort NE
static constexpr size_t OFF_NXB   = 150994944;               // ushort NE   (gxab)
static constexpr size_t OFF_EAB   = 167772160;               // ushort NE   (gaab)
static constexpr size_t OFF_AST   = 184549376;               // 512*512 ushort
static constexpr size_t OFF_WSP   = 185073664;
static constexpr size_t OFF_WSIL  = 185597952;
static constexpr size_t OFF_WOH   = 186122240;
static constexpr size_t OFF_WOUT  = 186646528;
static constexpr size_t OFF_WIGT  = 187170816;               // 4*128*128 ushort
static constexpr size_t OFF_WAGT  = 187301888;
static constexpr size_t OFF_POOL  = 187432960;               // 2048 uint
static constexpr size_t OFF_SCAL  = 187441152;               // 64 float (+ pmax u64[4] at +128)
static constexpr size_t OFF_SCALI = 187441408;               // 64 int
static constexpr size_t OFF_BMAX  = 187441664;               // 2048 float
static constexpr size_t OFF_BIDX  = 187449856;               // 2048 int
static constexpr size_t OFF_SSP   = 187458048;               // 2048 float
static constexpr size_t OFF_COMB  = 187466240;               // 65536 float
static constexpr size_t OFF_VALS  = 187728384;
static constexpr size_t OFF_IMP   = 187990528;
static constexpr size_t OFF_GMOE  = 188252672;
static constexpr size_t OFF_SEL   = 188514816;
static constexpr size_t WS_NEED   = 188776960;

extern "C" void kernel_launch(void* const* d_in, const int* in_sizes, int n_in,
                              void* d_out, int out_size, void* d_ws, size_t ws_size,
                              hipStream_t stream)
{
    (void)in_sizes; (void)n_in; (void)out_size;
    const float* x    = (const float*)d_in[0];
    const float* AS   = (const float*)d_in[1];
    const float* Wsp  = (const float*)d_in[2];
    const float* Wsil = (const float*)d_in[3];
    const float* Woh  = (const float*)d_in[4];
    const float* Wout = (const float*)d_in[5];
    const float* wig  = (const float*)d_in[6];
    const float* wag  = (const float*)d_in[7];
    const float* a_param = (const float*)d_in[8];
    const float* cls_w = (const float*)d_in[9];
    const float* cls_b = (const float*)d_in[10];
    const float* tokw  = (const float*)d_in[11];
    const float* prelu = (const float*)d_in[12];
    const float* tsw   = (const float*)d_in[13];
    const float* tsa   = (const float*)d_in[14];
    const float* tsb   = (const float*)d_in[15];
    const float* tsmix = (const float*)d_in[16];
    const float* p1a = (const float*)d_in[17];
    const float* p1b = (const float*)d_in[18];
    const float* p1m = (const float*)d_in[19];
    const float* p2a = (const float*)d_in[20];
    const float* p2b = (const float*)d_in[21];
    const float* p2m = (const float*)d_in[22];
    float* out = (float*)d_out;

    char* w = (char*)d_ws;
    if (ws_size < WS_NEED) { sentinel_k<<<1, 256, 0, stream>>>(out); return; }

    ushort* xb    = (ushort*)(w + OFF_XB);
    ushort* tmpb  = (ushort*)(w + OFF_TMPB);
    ushort* spb   = (ushort*)(w + OFF_SPB);
    ushort* spT   = (ushort*)(w + OFF_SPT);
    float*  dbuf  = (float*)(w + OFF_DBUF);
    float*  Hbuf  = (float*)(w + OFF_HBUF);
    ushort* Sb    = (ushort*)(w + OFF_DBUF);   // alias
    ushort* Pb    = (ushort*)(w + OFF_HBUF);   // alias
    float*  pvpart= (float*)(w + OFF_XB);      // alias (32MB: XB+TMPB), attention-pool only
    int*    rankp = (int*)(w + OFF_DBUF);      // alias, ts2 only
    ushort* gatedb= (ushort*)(w + OFF_GATB);
    ushort* gxab  = (ushort*)(w + OFF_NXB);
    ushort* gaab  = (ushort*)(w + OFF_EAB);
    ushort* ASt   = (ushort*)(w + OFF_AST);
    ushort* Wspb  = (ushort*)(w + OFF_WSP);
    ushort* Wsilb = (ushort*)(w + OFF_WSIL);
    ushort* Wohb  = (ushort*)(w + OFF_WOH);
    ushort* Woutb = (ushort*)(w + OFF_WOUT);
    ushort* wigT  = (ushort*)(w + OFF_WIGT);
    ushort* wagT  = (ushort*)(w + OFF_WAGT);
    uint*   poolU = (uint*)(w + OFF_POOL);
    float*  scal  = (float*)(w + OFF_SCAL);
    u64*    pmax  = (u64*)(w + OFF_SCAL + 128);
    int*    scalI = (int*)(w + OFF_SCALI);
    float*  bmax  = (float*)(w + OFF_BMAX);
    int*    bidx  = (int*)(w + OFF_BIDX);
    float*  sspart= (float*)(w + OFF_SSP);
    float*  comb  = (float*)(w + OFF_COMB);
    float*  vals  = (float*)(w + OFF_VALS);
    float*  imp   = (float*)(w + OFF_IMP);
    float*  gmoe  = (float*)(w + OFF_GMOE);
    float*  sel   = (float*)(w + OFF_SEL);
    ushort* gsb     = tmpb;   // reuse (after attention pool)
    ushort* probs2b = xb;     // reuse (after attention pool)

    // ---- prep ----
    convert_f2b_k<<<2048, 256, 0, stream>>>(x, xb, NE >> 2);
    convert_w4_k<<<dim3(256, 4), 256, 0, stream>>>(Wsp, Wsil, Woh, Wout, Wspb);
    transpose_to_bf16<true><<<dim3(16, 16, 1), 256, 0, stream>>>(AS, ASt, 512, 512);
    transpose_gates_k<<<dim3(4, 4, 8), 256, 0, stream>>>(wig, wag, wigT, wagT);
    init_misc_k<<<8, 256, 0, stream>>>(poolU, pmax);

    // ---- gate pre-acts (bf16), kept in NXB/EAB until after pool ----
    gate_gemm_k<<<dim3(2, 128, 4), 256, 0, stream>>>(xb, wigT, wagT, gxab, gaab);

    // ---- G1: tmp = x @ AS ; G2: spatial = tmp @ Wsp^T ----
    gemm_bt<1, false><<<dim3(4, 128), 256, 0, stream>>>(xb, 512, ASt, 512, tmpb, 512, 512, nullptr, nullptr);
    gemm_bt<1, false><<<dim3(4, 128), 256, 0, stream>>>(tmpb, 512, Wspb, 512, spb, 512, 512, nullptr, nullptr);

    // ---- attention pool (per batch) ----
    transpose_to_bf16<false><<<dim3(16, 128, 4), 256, 0, stream>>>(spb, spT, 4096, 512);
    const float sc128 = 0.0883883476f;
    for (int b = 0; b < 4; b++) {
        const ushort* spB = spb + (size_t)b * L_ * D_;
        gemm_bt<1, false><<<dim3(32, 32), 256, 0, stream>>>(spB, 512, spB, 512, Sb, 4096, 512, nullptr, nullptr);
        softmax_rows_k<<<4096, 256, 0, stream>>>(Sb, Pb, sc128);
        pv_split_k<<<dim3(4, 32, 4), 256, 0, stream>>>(Pb, spT + (size_t)b * D_ * L_, pvpart);
        pool_combine_k<<<128, 256, 0, stream>>>(pvpart, poolU + b * 512);
    }

    // ---- fused gates+gated ----
    gates_gated_k<<<1024, 256, 0, stream>>>(x, gxab, gaab, a_param, poolU, gatedb);

    // ---- sparsity = ripple_act(gated @ Wsil^T) ; gs = gated * sparsity ----
    gemm_bt<0, true><<<dim3(4, 128), 256, 0, stream>>>(gatedb, 512, Wsilb, 512, dbuf, 512, 512, nullptr, &pmax[0]);
    ripple_g_k<<<2048, 256, 0, stream>>>(dbuf, Hbuf, sspart, &pmax[0], p1a, p1b, p1m);
    redsum2_k<<<1, 256, 0, stream>>>(sspart, 2048, &scal[1]);
    ripple_softmax_k<1><<<16384, 256, 0, stream>>>(Hbuf, &pmax[0], &scal[1], p1a, gatedb, gsb);

    // ---- token selection -> sel ----
    ts1_k<<<4096, 256, 0, stream>>>(x, cls_w, cls_b, tokw, prelu, comb, vals);
    ts2a_k<<<dim3(16, 8, 4), 256, 0, stream>>>(comb, rankp);
    ts2b_k<<<dim3(16, 4), 256, 0, stream>>>(rankp, vals, imp);
    redmax1_k<<<64, 256, 0, stream>>>(imp, 65536, bmax, bidx);
    redmax2_k<<<1, 256, 0, stream>>>(bmax, bidx, 64, &scal[4], &scalI[2]);
    moe_g_k<<<64, 256, 0, stream>>>(imp, gmoe, sspart, &scal[4], tsw, tsa, tsb, tsmix);
    redsum2_k<<<1, 256, 0, stream>>>(sspart, 64, &scal[5]);
    moe_sel_k<<<4, 256, 0, stream>>>(gmoe, &scal[4], &scalI[2], &scal[5], sel);

    // ---- attn = gs @ Woh^T, scaled by sel (fused max) ----
    gemm_bt<3, true><<<dim3(4, 128), 256, 0, stream>>>(gsb, 512, Wohb, 512, dbuf, 512, 512, sel, &pmax[1]);

    // ---- out_probs = ripple_act(d2) ----
    ripple_g_k<<<2048, 256, 0, stream>>>(dbuf, Hbuf, sspart, &pmax[1], p2a, p2b, p2m);
    redsum2_k<<<1, 256, 0, stream>>>(sspart, 2048, &scal[3]);
    ripple_softmax_k<0><<<16384, 256, 0, stream>>>(Hbuf, &pmax[1], &scal[3], p2a, nullptr, probs2b);

    // ---- out = probs @ Wout^T ----
    gemm_bt<0, false><<<dim3(4, 128), 256, 0, stream>>>(probs2b, 512, Woutb, 512, out, 512, 512, nullptr, nullptr);
}